// Round 9
// baseline (190.136 us; speedup 1.0000x reference)
//
#include <hip/hip_runtime.h>
#include <hip/hip_bf16.h>
#include <math.h>

#define NEG_SLOPE 0.2f

typedef short bf16x8 __attribute__((ext_vector_type(8)));
typedef float f32x4 __attribute__((ext_vector_type(4)));
typedef float f32x2 __attribute__((ext_vector_type(2)));

__device__ __forceinline__ float lrelu(float x) { return fmaxf(x, NEG_SLOPE * x); }

__device__ __forceinline__ ushort f2bf(float f) {
  __hip_bfloat16 b = __float2bfloat16(f);
  return *reinterpret_cast<ushort*>(&b);
}

// fp8 e4m3 (OCP on gfx950) scalar encode: low byte of packed result
__device__ __forceinline__ unsigned char f2fp8(float f) {
  return (unsigned char)(__builtin_amdgcn_cvt_pk_fp8_f32(f, f, 0, false) & 0xFF);
}

// ---------------- prep: Wg[144 cols][128 k] bf16, XOR-swizzled; also zeroes deg[].
// cols 0..127 = W1^T ; cols 128..135 = u_src[k][head] ; 136..143 = u_dst[k][head]
// where u[k][h] = sum_ch W1[k][h*16+ch] * att[h][ch]  (so  x @ u = h . att)
__global__ __launch_bounds__(256) void k_prep(
    const float* __restrict__ W1, const float* __restrict__ ats1, const float* __restrict__ atd1,
    ushort* __restrict__ Wg, int* __restrict__ deg, int N)
{
  int t = blockIdx.x * 256 + threadIdx.x;
  if (t < N) deg[t] = 0;
  if (t < 128 * 128) {
    int k = t >> 7, n = t & 127;
    Wg[(size_t)n * 128 + (k ^ ((n & 7) << 3))] = f2bf(W1[t]);
  } else if (t < 128 * 128 + 128 * 16) {
    int tt = t - 128 * 128;
    int k = tt >> 4;          // 0..127
    int c = tt & 15;          // 0..7 -> as, 8..15 -> ad
    int head = c & 7;
    const float* av = (c < 8) ? ats1 : atd1;
    float s = 0.f;
#pragma unroll
    for (int ch = 0; ch < 16; ++ch)
      s += W1[k * 128 + head * 16 + ch] * av[head * 16 + ch];
    int n = 128 + c;
    Wg[(size_t)n * 128 + (k ^ ((n & 7) << 3))] = f2bf(s);
  }
}

// ---------------- h1 = x @ W1 via bf16 MFMA, 64 nodes/block, 4 waves.
// 9 column tiles: 0..7 -> h1f (fp8 e4m3), tile 8 -> as1/ad1 (fp32)
__global__ __launch_bounds__(256) void k_gemm1m(
    const float* __restrict__ x, const ushort* __restrict__ Wg,
    unsigned char* __restrict__ h1f, float* __restrict__ as1, float* __restrict__ ad1, int N)
{
  __shared__ ushort Wls[144 * 128];
  const int tid = threadIdx.x;
  const float4* Wg4 = (const float4*)Wg;
  float4* Wl4 = (float4*)Wls;
#pragma unroll
  for (int i = 0; i < 9; ++i) Wl4[tid + i * 256] = Wg4[tid + i * 256];
  __syncthreads();

  const int lane = tid & 63, wid = tid >> 6;
  const int r0 = blockIdx.x * 64 + wid * 16;
  const int lr = lane & 15, kg = lane >> 4;
  int row = r0 + lr; if (row >= N) row = N - 1;
  const float* xr = x + (size_t)row * 128;

  f32x4 acc[9];
#pragma unroll
  for (int i = 0; i < 9; ++i) acc[i] = (f32x4){0.f, 0.f, 0.f, 0.f};

#pragma unroll
  for (int ks = 0; ks < 4; ++ks) {
    int k0 = ks * 32 + kg * 8;
    float4 xa = *(const float4*)(xr + k0);
    float4 xb = *(const float4*)(xr + k0 + 4);
    bf16x8 af;
    af[0] = f2bf(xa.x); af[1] = f2bf(xa.y); af[2] = f2bf(xa.z); af[3] = f2bf(xa.w);
    af[4] = f2bf(xb.x); af[5] = f2bf(xb.y); af[6] = f2bf(xb.z); af[7] = f2bf(xb.w);
#pragma unroll
    for (int nt = 0; nt < 9; ++nt) {
      int n = nt * 16 + lr;
      bf16x8 bfr = *(const bf16x8*)(Wls + n * 128 + (k0 ^ ((n & 7) << 3)));
      acc[nt] = __builtin_amdgcn_mfma_f32_16x16x32_bf16(af, bfr, acc[nt], 0, 0, 0);
    }
  }
  // C layout: col = lane&15, row = (lane>>4)*4 + reg
#pragma unroll
  for (int nt = 0; nt < 8; ++nt) {
#pragma unroll
    for (int i = 0; i < 4; ++i) {
      int r = r0 + kg * 4 + i;
      if (r < N) h1f[(size_t)r * 128 + nt * 16 + lr] = f2fp8(acc[nt][i]);
    }
  }
#pragma unroll
  for (int i = 0; i < 4; ++i) {
    int r = r0 + kg * 4 + i;
    if (r < N) {
      if (lr < 8) as1[(size_t)r * 8 + lr]     = acc[8][i];
      else        ad1[(size_t)r * 8 + lr - 8] = acc[8][i];
    }
  }
}

// ---------------- CSR build: histogram, 2-level exclusive scan, scatter
__global__ __launch_bounds__(256) void k_hist(const int* __restrict__ ei, int E, int N,
                                              int* __restrict__ deg) {
  int e = blockIdx.x * 256 + threadIdx.x;
  if (e >= E + N) return;
  int d = (e < E) ? ei[E + e] : e - E;
  atomicAdd(&deg[d], 1);
}

__global__ __launch_bounds__(256) void k_scan1(const int* __restrict__ deg,
                                               int* __restrict__ rowptr,
                                               int* __restrict__ bsum, int N) {
  __shared__ int sc[256];
  int b = blockIdx.x, t = threadIdx.x;
  int i0 = b * 512 + 2 * t, i1 = i0 + 1;
  int a = (i0 < N) ? deg[i0] : 0;
  int bb = (i1 < N) ? deg[i1] : 0;
  int s = a + bb;
  sc[t] = s; __syncthreads();
  int run = s;
  for (int dd = 1; dd < 256; dd <<= 1) {
    int v = (t >= dd) ? sc[t - dd] : 0; __syncthreads();
    run += v; sc[t] = run; __syncthreads();
  }
  int excl = run - s;
  if (i0 < N) rowptr[i0] = excl;
  if (i1 < N) rowptr[i1] = excl + a;
  if (t == 255) bsum[b] = run;
}

__global__ __launch_bounds__(256) void k_scan2(int* __restrict__ bsum, int nb) {
  __shared__ int sc[256];
  int t = threadIdx.x;
  int s = (t < nb) ? bsum[t] : 0;
  sc[t] = s; __syncthreads();
  int run = s;
  for (int dd = 1; dd < 256; dd <<= 1) {
    int v = (t >= dd) ? sc[t - dd] : 0; __syncthreads();
    run += v; sc[t] = run; __syncthreads();
  }
  if (t < nb) bsum[t] = run - s;
}

__global__ __launch_bounds__(256) void k_scan3(int* __restrict__ rowptr,
                                               const int* __restrict__ bsum,
                                               int* __restrict__ cursor, int N) {
  int i = blockIdx.x * 256 + threadIdx.x;
  if (i >= N) return;
  int v = rowptr[i] + bsum[i >> 9];
  rowptr[i] = v;
  cursor[i] = v;
}

__global__ __launch_bounds__(256) void k_scatter(const int* __restrict__ ei, int E, int N,
                                                 int* __restrict__ cursor,
                                                 int* __restrict__ srt) {
  int e = blockIdx.x * 256 + threadIdx.x;
  if (e >= E + N) return;
  int s, d;
  if (e < E) { s = ei[e]; d = ei[E + e]; } else { s = d = e - E; }
  int pos = atomicAdd(&cursor[d], 1);
  srt[pos] = s;
}

// ---------------- Fused layer-1, PERSISTENT waves; fp8 h rows (1 line/edge).
// Per node: 4 edge-groups x 16 lanes x 8 ch, unroll-2. W2/b1/att2 hoisted;
// int addressing; __expf-based ELU.
__global__ __launch_bounds__(256) void k_agg1f(
    const int* __restrict__ rowptr, const int* __restrict__ deg, const int* __restrict__ srt,
    const float* __restrict__ as1, const float* __restrict__ ad1,
    const unsigned char* __restrict__ h1f,
    const float* __restrict__ b1, const float* __restrict__ W2,
    const float* __restrict__ ats2, const float* __restrict__ atd2,
    float4* __restrict__ nd2, int N)
{
  const int lane = threadIdx.x & 63;
  const int wv = blockIdx.x * 4 + (threadIdx.x >> 6);
  const int nw = gridDim.x * 4;
  const int g = lane >> 4, l16 = lane & 15;
  const int hh = l16 >> 1;                 // head of this lane's 8 channels
  const int hoff = 8 * l16;

  // hoisted uniforms (constant across nodes)
  const float4* W24 = (const float4*)(W2 + 16 * l16);
  const float4 w0 = W24[0], w1 = W24[1], w2 = W24[2], w3 = W24[3];
  const float4 b0 = *(const float4*)(b1 + hoff);
  const float4 b4 = *(const float4*)(b1 + hoff + 4);
  const float s2x = ats2[0], s2y = ats2[1];
  const float d2x = atd2[0], d2y = atd2[1];

  for (int d = wv; d < N; d += nw) {
    const int start = rowptr[d];
    const int dg = deg[d];
    const float adh = ad1[d * 8 + hh];

    f32x4 accA = (f32x4){0.f,0.f,0.f,0.f}, accB = (f32x4){0.f,0.f,0.f,0.f};
    float sum = 0.f;

    int c = g;
    int sa = srt[start + min(c,     dg - 1)];
    int sb = srt[start + min(c + 4, dg - 1)];
    while (c < dg) {
      int cn = c + 8;
      int sa2 = srt[start + min(cn,     dg - 1)];
      int sb2 = srt[start + min(cn + 4, dg - 1)];
      float ava = as1[sa * 8 + hh];
      uint2 hva = *(const uint2*)(h1f + sa * 128 + hoff);
      float avb = as1[sb * 8 + hh];
      uint2 hvb = *(const uint2*)(h1f + sb * 128 + hoff);

      float aua = __expf(lrelu(ava + adh));
      float aub = (c + 4 < dg) ? __expf(lrelu(avb + adh)) : 0.f;
      sum += aua + aub;
      {
        f32x2 c01 = __builtin_amdgcn_cvt_pk_f32_fp8(hva.x, 0);
        f32x2 c23 = __builtin_amdgcn_cvt_pk_f32_fp8(hva.x, 1);
        f32x2 c45 = __builtin_amdgcn_cvt_pk_f32_fp8(hva.y, 0);
        f32x2 c67 = __builtin_amdgcn_cvt_pk_f32_fp8(hva.y, 1);
        accA[0] = fmaf(aua, c01[0], accA[0]); accA[1] = fmaf(aua, c01[1], accA[1]);
        accA[2] = fmaf(aua, c23[0], accA[2]); accA[3] = fmaf(aua, c23[1], accA[3]);
        accB[0] = fmaf(aua, c45[0], accB[0]); accB[1] = fmaf(aua, c45[1], accB[1]);
        accB[2] = fmaf(aua, c67[0], accB[2]); accB[3] = fmaf(aua, c67[1], accB[3]);
      }
      {
        f32x2 c01 = __builtin_amdgcn_cvt_pk_f32_fp8(hvb.x, 0);
        f32x2 c23 = __builtin_amdgcn_cvt_pk_f32_fp8(hvb.x, 1);
        f32x2 c45 = __builtin_amdgcn_cvt_pk_f32_fp8(hvb.y, 0);
        f32x2 c67 = __builtin_amdgcn_cvt_pk_f32_fp8(hvb.y, 1);
        accA[0] = fmaf(aub, c01[0], accA[0]); accA[1] = fmaf(aub, c01[1], accA[1]);
        accA[2] = fmaf(aub, c23[0], accA[2]); accA[3] = fmaf(aub, c23[1], accA[3]);
        accB[0] = fmaf(aub, c45[0], accB[0]); accB[1] = fmaf(aub, c45[1], accB[1]);
        accB[2] = fmaf(aub, c67[0], accB[2]); accB[3] = fmaf(aub, c67[1], accB[3]);
      }

      c = cn; sa = sa2; sb = sb2;
    }
#pragma unroll
    for (int i = 0; i < 4; ++i) {
      accA[i] += __shfl_xor(accA[i], 16); accA[i] += __shfl_xor(accA[i], 32);
      accB[i] += __shfl_xor(accB[i], 16); accB[i] += __shfl_xor(accB[i], 32);
    }
    sum += __shfl_xor(sum, 16); sum += __shfl_xor(sum, 32);
    const float inv = 1.f / (sum + 1e-16f);

    // epilogue: normalize, +b1, ELU (exp-1), GEMM2 (128->2), layer-2 att dots
    float v[8];
    v[0] = fmaf(accA[0], inv, b0.x); v[1] = fmaf(accA[1], inv, b0.y);
    v[2] = fmaf(accA[2], inv, b0.z); v[3] = fmaf(accA[3], inv, b0.w);
    v[4] = fmaf(accB[0], inv, b4.x); v[5] = fmaf(accB[1], inv, b4.y);
    v[6] = fmaf(accB[2], inv, b4.z); v[7] = fmaf(accB[3], inv, b4.w);
#pragma unroll
    for (int j = 0; j < 8; ++j) v[j] = v[j] > 0.f ? v[j] : (__expf(v[j]) - 1.f);

    float p0 = v[0]*w0.x + v[1]*w0.z + v[2]*w1.x + v[3]*w1.z
             + v[4]*w2.x + v[5]*w2.z + v[6]*w3.x + v[7]*w3.z;
    float p1 = v[0]*w0.y + v[1]*w0.w + v[2]*w1.y + v[3]*w1.w
             + v[4]*w2.y + v[5]*w2.w + v[6]*w3.y + v[7]*w3.w;
#pragma unroll
    for (int m = 1; m < 16; m <<= 1) { p0 += __shfl_xor(p0, m); p1 += __shfl_xor(p1, m); }
    if (lane == 0) {
      float a2 = p0 * s2x + p1 * s2y;
      float dd2 = p0 * d2x + p1 * d2y;
      nd2[d] = make_float4(p0, p1, a2, dd2);
    }
  }
}

// ---------------- Fused layer-2: 16 lanes per dst; one float4 load per edge
__global__ __launch_bounds__(256) void k_agg2f(
    const int* __restrict__ rowptr, const int* __restrict__ deg, const int* __restrict__ srt,
    const float4* __restrict__ nd2, const float* __restrict__ b2,
    float* __restrict__ out, int N)
{
  const int l16 = threadIdx.x & 15;
  const int d = blockIdx.x * 16 + (threadIdx.x >> 4);
  if (d >= N) return;
  const int start = rowptr[d];
  const int dg = deg[d];
  const float adv = nd2[d].w;

  float se = 0.f, a0 = 0.f, a1 = 0.f;
  for (int c = l16; c < dg; c += 16) {
    int s = srt[start + c];
    float4 r = nd2[s];
    float ex = __expf(lrelu(r.z + adv));
    se += ex;
    a0 = fmaf(ex, r.x, a0);
    a1 = fmaf(ex, r.y, a1);
  }
#pragma unroll
  for (int m = 1; m < 16; m <<= 1) {
    se += __shfl_xor(se, m, 16);
    a0 += __shfl_xor(a0, m, 16);
    a1 += __shfl_xor(a1, m, 16);
  }
  if (l16 == 0) {
    float invs = 1.f / (se + 1e-16f);
    out[(size_t)d * 2]     = a0 * invs + b2[0];
    out[(size_t)d * 2 + 1] = a1 * invs + b2[1];
  }
}

extern "C" void kernel_launch(void* const* d_in, const int* in_sizes, int n_in,
                              void* d_out, int out_size, void* d_ws, size_t ws_size,
                              hipStream_t stream) {
  const float* x    = (const float*)d_in[0];
  const int*   ei   = (const int*)d_in[1];
  const float* W1   = (const float*)d_in[2];
  const float* ats1 = (const float*)d_in[3];
  const float* atd1 = (const float*)d_in[4];
  const float* b1   = (const float*)d_in[5];
  const float* W2   = (const float*)d_in[6];
  const float* ats2 = (const float*)d_in[7];
  const float* atd2 = (const float*)d_in[8];
  const float* b2   = (const float*)d_in[9];
  float* out = (float*)d_out;

  const int N  = in_sizes[0] / 128;
  const int E  = in_sizes[1] / 2;
  const int E2 = E + N;
  const int nb = (N + 511) / 512;

  // workspace layout (floats)
  float* ws = (float*)d_ws;
  size_t off = 0;
  unsigned char* h1f = (unsigned char*)(ws + off); off += (size_t)N * 32;  // N*128 fp8
  float* as1 = ws + off; off += (size_t)N * 8;
  float* ad1 = ws + off; off += (size_t)N * 8;
  float4* nd2 = (float4*)(ws + off); off += (size_t)N * 4;
  int* deg    = (int*)(ws + off); off += (size_t)N;
  int* rowptr = (int*)(ws + off); off += (size_t)N;
  int* cursor = (int*)(ws + off); off += (size_t)N;
  int* bsum   = (int*)(ws + off); off += 256;
  int* srt    = (int*)(ws + off); off += (size_t)E2;
  ushort* Wg  = (ushort*)(ws + off); off += 144 * 64;         // 144*128 bf16

  // prep (also zeroes deg) must run before hist
  const int prep_blocks = max((128 * 128 + 128 * 16 + 255) / 256, (N + 255) / 256);
  k_prep<<<prep_blocks, 256, 0, stream>>>(W1, ats1, atd1, Wg, deg, N);

  // CSR build (shared by both layers)
  k_hist<<<(E2 + 255) / 256, 256, 0, stream>>>(ei, E, N, deg);
  k_scan1<<<nb, 256, 0, stream>>>(deg, rowptr, bsum, N);
  k_scan2<<<1, 256, 0, stream>>>(bsum, nb);
  k_scan3<<<(N + 255) / 256, 256, 0, stream>>>(rowptr, bsum, cursor, N);
  k_scatter<<<(E2 + 255) / 256, 256, 0, stream>>>(ei, E, N, cursor, srt);

  // layer-1 GEMM (bf16 MFMA) with fused attention-dot columns, fp8 h output
  k_gemm1m<<<(N + 63) / 64, 256, 0, stream>>>(x, Wg, h1f, as1, ad1, N);

  // fused layer-1 softmax+aggregate+ELU+GEMM2+att dots (persistent waves)
  k_agg1f<<<2048, 256, 0, stream>>>(rowptr, deg, srt, as1, ad1, h1f,
                                    b1, W2, ats2, atd2, nd2, N);

  // fused layer-2
  k_agg2f<<<(N + 15) / 16, 256, 0, stream>>>(rowptr, deg, srt, nd2, b2, out, N);
}

// Round 10
// 186.085 us; speedup vs baseline: 1.0218x; 1.0218x over previous
//
#include <hip/hip_runtime.h>
#include <hip/hip_bf16.h>
#include <math.h>

#define NEG_SLOPE 0.2f

typedef short bf16x8 __attribute__((ext_vector_type(8)));
typedef float f32x4 __attribute__((ext_vector_type(4)));
typedef float f32x2 __attribute__((ext_vector_type(2)));

__device__ __forceinline__ float lrelu(float x) { return fmaxf(x, NEG_SLOPE * x); }

__device__ __forceinline__ ushort f2bf(float f) {
  __hip_bfloat16 b = __float2bfloat16(f);
  return *reinterpret_cast<ushort*>(&b);
}

// fp8 e4m3 (OCP on gfx950) scalar encode: low byte of packed result
__device__ __forceinline__ unsigned char f2fp8(float f) {
  return (unsigned char)(__builtin_amdgcn_cvt_pk_fp8_f32(f, f, 0, false) & 0xFF);
}

// ---------------- prep: Wg[144 cols][128 k] bf16, XOR-swizzled; also zeroes deg[].
// cols 0..127 = W1^T ; cols 128..135 = u_src[k][head] ; 136..143 = u_dst[k][head]
// where u[k][h] = sum_ch W1[k][h*16+ch] * att[h][ch]  (so  x @ u = h . att)
__global__ __launch_bounds__(256) void k_prep(
    const float* __restrict__ W1, const float* __restrict__ ats1, const float* __restrict__ atd1,
    ushort* __restrict__ Wg, int* __restrict__ deg, int N)
{
  int t = blockIdx.x * 256 + threadIdx.x;
  if (t < N) deg[t] = 0;
  if (t < 128 * 128) {
    int k = t >> 7, n = t & 127;
    Wg[(size_t)n * 128 + (k ^ ((n & 7) << 3))] = f2bf(W1[t]);
  } else if (t < 128 * 128 + 128 * 16) {
    int tt = t - 128 * 128;
    int k = tt >> 4;          // 0..127
    int c = tt & 15;          // 0..7 -> as, 8..15 -> ad
    int head = c & 7;
    const float* av = (c < 8) ? ats1 : atd1;
    float s = 0.f;
#pragma unroll
    for (int ch = 0; ch < 16; ++ch)
      s += W1[k * 128 + head * 16 + ch] * av[head * 16 + ch];
    int n = 128 + c;
    Wg[(size_t)n * 128 + (k ^ ((n & 7) << 3))] = f2bf(s);
  }
}

// ---------------- h1 = x @ W1 via bf16 MFMA, 64 nodes/block, 4 waves.
// 9 column tiles: 0..7 -> h1f (fp8 e4m3), tile 8 -> as1/ad1 (fp32)
__global__ __launch_bounds__(256) void k_gemm1m(
    const float* __restrict__ x, const ushort* __restrict__ Wg,
    unsigned char* __restrict__ h1f, float* __restrict__ as1, float* __restrict__ ad1, int N)
{
  __shared__ ushort Wls[144 * 128];
  const int tid = threadIdx.x;
  const float4* Wg4 = (const float4*)Wg;
  float4* Wl4 = (float4*)Wls;
#pragma unroll
  for (int i = 0; i < 9; ++i) Wl4[tid + i * 256] = Wg4[tid + i * 256];
  __syncthreads();

  const int lane = tid & 63, wid = tid >> 6;
  const int r0 = blockIdx.x * 64 + wid * 16;
  const int lr = lane & 15, kg = lane >> 4;
  int row = r0 + lr; if (row >= N) row = N - 1;
  const float* xr = x + (size_t)row * 128;

  f32x4 acc[9];
#pragma unroll
  for (int i = 0; i < 9; ++i) acc[i] = (f32x4){0.f, 0.f, 0.f, 0.f};

#pragma unroll
  for (int ks = 0; ks < 4; ++ks) {
    int k0 = ks * 32 + kg * 8;
    float4 xa = *(const float4*)(xr + k0);
    float4 xb = *(const float4*)(xr + k0 + 4);
    bf16x8 af;
    af[0] = f2bf(xa.x); af[1] = f2bf(xa.y); af[2] = f2bf(xa.z); af[3] = f2bf(xa.w);
    af[4] = f2bf(xb.x); af[5] = f2bf(xb.y); af[6] = f2bf(xb.z); af[7] = f2bf(xb.w);
#pragma unroll
    for (int nt = 0; nt < 9; ++nt) {
      int n = nt * 16 + lr;
      bf16x8 bfr = *(const bf16x8*)(Wls + n * 128 + (k0 ^ ((n & 7) << 3)));
      acc[nt] = __builtin_amdgcn_mfma_f32_16x16x32_bf16(af, bfr, acc[nt], 0, 0, 0);
    }
  }
  // C layout: col = lane&15, row = (lane>>4)*4 + reg
#pragma unroll
  for (int nt = 0; nt < 8; ++nt) {
#pragma unroll
    for (int i = 0; i < 4; ++i) {
      int r = r0 + kg * 4 + i;
      if (r < N) h1f[(size_t)r * 128 + nt * 16 + lr] = f2fp8(acc[nt][i]);
    }
  }
#pragma unroll
  for (int i = 0; i < 4; ++i) {
    int r = r0 + kg * 4 + i;
    if (r < N) {
      if (lr < 8) as1[(size_t)r * 8 + lr]     = acc[8][i];
      else        ad1[(size_t)r * 8 + lr - 8] = acc[8][i];
    }
  }
}

// ---------------- CSR build: histogram, 2-level exclusive scan, scatter
__global__ __launch_bounds__(256) void k_hist(const int* __restrict__ ei, int E, int N,
                                              int* __restrict__ deg) {
  int e = blockIdx.x * 256 + threadIdx.x;
  if (e >= E + N) return;
  int d = (e < E) ? ei[E + e] : e - E;
  atomicAdd(&deg[d], 1);
}

__global__ __launch_bounds__(256) void k_scan1(const int* __restrict__ deg,
                                               int* __restrict__ rowptr,
                                               int* __restrict__ bsum, int N) {
  __shared__ int sc[256];
  int b = blockIdx.x, t = threadIdx.x;
  int i0 = b * 512 + 2 * t, i1 = i0 + 1;
  int a = (i0 < N) ? deg[i0] : 0;
  int bb = (i1 < N) ? deg[i1] : 0;
  int s = a + bb;
  sc[t] = s; __syncthreads();
  int run = s;
  for (int dd = 1; dd < 256; dd <<= 1) {
    int v = (t >= dd) ? sc[t - dd] : 0; __syncthreads();
    run += v; sc[t] = run; __syncthreads();
  }
  int excl = run - s;
  if (i0 < N) rowptr[i0] = excl;
  if (i1 < N) rowptr[i1] = excl + a;
  if (t == 255) bsum[b] = run;
}

__global__ __launch_bounds__(256) void k_scan2(int* __restrict__ bsum, int nb) {
  __shared__ int sc[256];
  int t = threadIdx.x;
  int s = (t < nb) ? bsum[t] : 0;
  sc[t] = s; __syncthreads();
  int run = s;
  for (int dd = 1; dd < 256; dd <<= 1) {
    int v = (t >= dd) ? sc[t - dd] : 0; __syncthreads();
    run += v; sc[t] = run; __syncthreads();
  }
  if (t < nb) bsum[t] = run - s;
}

__global__ __launch_bounds__(256) void k_scan3(int* __restrict__ rowptr,
                                               const int* __restrict__ bsum,
                                               int* __restrict__ cursor, int N) {
  int i = blockIdx.x * 256 + threadIdx.x;
  if (i >= N) return;
  int v = rowptr[i] + bsum[i >> 9];
  rowptr[i] = v;
  cursor[i] = v;
}

__global__ __launch_bounds__(256) void k_scatter(const int* __restrict__ ei, int E, int N,
                                                 int* __restrict__ cursor,
                                                 int* __restrict__ srt) {
  int e = blockIdx.x * 256 + threadIdx.x;
  if (e >= E + N) return;
  int s, d;
  if (e < E) { s = ei[e]; d = ei[E + e]; } else { s = d = e - E; }
  int pos = atomicAdd(&cursor[d], 1);
  srt[pos] = s;
}

// ---------------- Fused layer-1, BLOCKWISE (4 dst/block, high occupancy) + lean
// epilogue + fp8 h rows. Per node: 4 edge-groups x 16 lanes x 8 ch, unroll-2.
__global__ __launch_bounds__(256) void k_agg1f(
    const int* __restrict__ rowptr, const int* __restrict__ deg, const int* __restrict__ srt,
    const float* __restrict__ as1, const float* __restrict__ ad1,
    const unsigned char* __restrict__ h1f,
    const float* __restrict__ b1, const float* __restrict__ W2,
    const float* __restrict__ ats2, const float* __restrict__ atd2,
    float4* __restrict__ nd2, int N)
{
  const int lane = threadIdx.x & 63;
  const int d = blockIdx.x * 4 + (threadIdx.x >> 6);
  if (d >= N) return;
  const int g = lane >> 4, l16 = lane & 15;
  const int hh = l16 >> 1;                 // head of this lane's 8 channels
  const int hoff = 8 * l16;

  // per-wave uniforms (L2-resident)
  const float4* W24 = (const float4*)(W2 + 16 * l16);
  const float4 w0 = W24[0], w1 = W24[1], w2 = W24[2], w3 = W24[3];
  const float4 b0 = *(const float4*)(b1 + hoff);
  const float4 b4 = *(const float4*)(b1 + hoff + 4);
  const float s2x = ats2[0], s2y = ats2[1];
  const float d2x = atd2[0], d2y = atd2[1];

  const int start = rowptr[d];
  const int dg = deg[d];
  const float adh = ad1[d * 8 + hh];

  f32x4 accA = (f32x4){0.f,0.f,0.f,0.f}, accB = (f32x4){0.f,0.f,0.f,0.f};
  float sum = 0.f;

  int c = g;
  int sa = srt[start + min(c,     dg - 1)];
  int sb = srt[start + min(c + 4, dg - 1)];
  while (c < dg) {
    int cn = c + 8;
    int sa2 = srt[start + min(cn,     dg - 1)];
    int sb2 = srt[start + min(cn + 4, dg - 1)];
    float ava = as1[sa * 8 + hh];
    uint2 hva = *(const uint2*)(h1f + sa * 128 + hoff);
    float avb = as1[sb * 8 + hh];
    uint2 hvb = *(const uint2*)(h1f + sb * 128 + hoff);

    float aua = __expf(lrelu(ava + adh));
    float aub = (c + 4 < dg) ? __expf(lrelu(avb + adh)) : 0.f;
    sum += aua + aub;
    {
      f32x2 c01 = __builtin_amdgcn_cvt_pk_f32_fp8(hva.x, 0);
      f32x2 c23 = __builtin_amdgcn_cvt_pk_f32_fp8(hva.x, 1);
      f32x2 c45 = __builtin_amdgcn_cvt_pk_f32_fp8(hva.y, 0);
      f32x2 c67 = __builtin_amdgcn_cvt_pk_f32_fp8(hva.y, 1);
      accA[0] = fmaf(aua, c01[0], accA[0]); accA[1] = fmaf(aua, c01[1], accA[1]);
      accA[2] = fmaf(aua, c23[0], accA[2]); accA[3] = fmaf(aua, c23[1], accA[3]);
      accB[0] = fmaf(aua, c45[0], accB[0]); accB[1] = fmaf(aua, c45[1], accB[1]);
      accB[2] = fmaf(aua, c67[0], accB[2]); accB[3] = fmaf(aua, c67[1], accB[3]);
    }
    {
      f32x2 c01 = __builtin_amdgcn_cvt_pk_f32_fp8(hvb.x, 0);
      f32x2 c23 = __builtin_amdgcn_cvt_pk_f32_fp8(hvb.x, 1);
      f32x2 c45 = __builtin_amdgcn_cvt_pk_f32_fp8(hvb.y, 0);
      f32x2 c67 = __builtin_amdgcn_cvt_pk_f32_fp8(hvb.y, 1);
      accA[0] = fmaf(aub, c01[0], accA[0]); accA[1] = fmaf(aub, c01[1], accA[1]);
      accA[2] = fmaf(aub, c23[0], accA[2]); accA[3] = fmaf(aub, c23[1], accA[3]);
      accB[0] = fmaf(aub, c45[0], accB[0]); accB[1] = fmaf(aub, c45[1], accB[1]);
      accB[2] = fmaf(aub, c67[0], accB[2]); accB[3] = fmaf(aub, c67[1], accB[3]);
    }

    c = cn; sa = sa2; sb = sb2;
  }
#pragma unroll
  for (int i = 0; i < 4; ++i) {
    accA[i] += __shfl_xor(accA[i], 16); accA[i] += __shfl_xor(accA[i], 32);
    accB[i] += __shfl_xor(accB[i], 16); accB[i] += __shfl_xor(accB[i], 32);
  }
  sum += __shfl_xor(sum, 16); sum += __shfl_xor(sum, 32);
  const float inv = 1.f / (sum + 1e-16f);

  // epilogue: normalize, +b1, ELU (exp-1), GEMM2 (128->2), layer-2 att dots
  float v[8];
  v[0] = fmaf(accA[0], inv, b0.x); v[1] = fmaf(accA[1], inv, b0.y);
  v[2] = fmaf(accA[2], inv, b0.z); v[3] = fmaf(accA[3], inv, b0.w);
  v[4] = fmaf(accB[0], inv, b4.x); v[5] = fmaf(accB[1], inv, b4.y);
  v[6] = fmaf(accB[2], inv, b4.z); v[7] = fmaf(accB[3], inv, b4.w);
#pragma unroll
  for (int j = 0; j < 8; ++j) v[j] = v[j] > 0.f ? v[j] : (__expf(v[j]) - 1.f);

  float p0 = v[0]*w0.x + v[1]*w0.z + v[2]*w1.x + v[3]*w1.z
           + v[4]*w2.x + v[5]*w2.z + v[6]*w3.x + v[7]*w3.z;
  float p1 = v[0]*w0.y + v[1]*w0.w + v[2]*w1.y + v[3]*w1.w
           + v[4]*w2.y + v[5]*w2.w + v[6]*w3.y + v[7]*w3.w;
#pragma unroll
  for (int m = 1; m < 16; m <<= 1) { p0 += __shfl_xor(p0, m); p1 += __shfl_xor(p1, m); }
  if (lane == 0) {
    float a2 = p0 * s2x + p1 * s2y;
    float dd2 = p0 * d2x + p1 * d2y;
    nd2[d] = make_float4(p0, p1, a2, dd2);
  }
}

// ---------------- Fused layer-2: 16 lanes per dst; one float4 load per edge
__global__ __launch_bounds__(256) void k_agg2f(
    const int* __restrict__ rowptr, const int* __restrict__ deg, const int* __restrict__ srt,
    const float4* __restrict__ nd2, const float* __restrict__ b2,
    float* __restrict__ out, int N)
{
  const int l16 = threadIdx.x & 15;
  const int d = blockIdx.x * 16 + (threadIdx.x >> 4);
  if (d >= N) return;
  const int start = rowptr[d];
  const int dg = deg[d];
  const float adv = nd2[d].w;

  float se = 0.f, a0 = 0.f, a1 = 0.f;
  for (int c = l16; c < dg; c += 16) {
    int s = srt[start + c];
    float4 r = nd2[s];
    float ex = __expf(lrelu(r.z + adv));
    se += ex;
    a0 = fmaf(ex, r.x, a0);
    a1 = fmaf(ex, r.y, a1);
  }
#pragma unroll
  for (int m = 1; m < 16; m <<= 1) {
    se += __shfl_xor(se, m, 16);
    a0 += __shfl_xor(a0, m, 16);
    a1 += __shfl_xor(a1, m, 16);
  }
  if (l16 == 0) {
    float invs = 1.f / (se + 1e-16f);
    out[(size_t)d * 2]     = a0 * invs + b2[0];
    out[(size_t)d * 2 + 1] = a1 * invs + b2[1];
  }
}

extern "C" void kernel_launch(void* const* d_in, const int* in_sizes, int n_in,
                              void* d_out, int out_size, void* d_ws, size_t ws_size,
                              hipStream_t stream) {
  const float* x    = (const float*)d_in[0];
  const int*   ei   = (const int*)d_in[1];
  const float* W1   = (const float*)d_in[2];
  const float* ats1 = (const float*)d_in[3];
  const float* atd1 = (const float*)d_in[4];
  const float* b1   = (const float*)d_in[5];
  const float* W2   = (const float*)d_in[6];
  const float* ats2 = (const float*)d_in[7];
  const float* atd2 = (const float*)d_in[8];
  const float* b2   = (const float*)d_in[9];
  float* out = (float*)d_out;

  const int N  = in_sizes[0] / 128;
  const int E  = in_sizes[1] / 2;
  const int E2 = E + N;
  const int nb = (N + 511) / 512;

  // workspace layout (floats)
  float* ws = (float*)d_ws;
  size_t off = 0;
  unsigned char* h1f = (unsigned char*)(ws + off); off += (size_t)N * 32;  // N*128 fp8
  float* as1 = ws + off; off += (size_t)N * 8;
  float* ad1 = ws + off; off += (size_t)N * 8;
  float4* nd2 = (float4*)(ws + off); off += (size_t)N * 4;
  int* deg    = (int*)(ws + off); off += (size_t)N;
  int* rowptr = (int*)(ws + off); off += (size_t)N;
  int* cursor = (int*)(ws + off); off += (size_t)N;
  int* bsum   = (int*)(ws + off); off += 256;
  int* srt    = (int*)(ws + off); off += (size_t)E2;
  ushort* Wg  = (ushort*)(ws + off); off += 144 * 64;         // 144*128 bf16

  // prep (also zeroes deg) must run before hist
  const int prep_blocks = max((128 * 128 + 128 * 16 + 255) / 256, (N + 255) / 256);
  k_prep<<<prep_blocks, 256, 0, stream>>>(W1, ats1, atd1, Wg, deg, N);

  // CSR build (shared by both layers)
  k_hist<<<(E2 + 255) / 256, 256, 0, stream>>>(ei, E, N, deg);
  k_scan1<<<nb, 256, 0, stream>>>(deg, rowptr, bsum, N);
  k_scan2<<<1, 256, 0, stream>>>(bsum, nb);
  k_scan3<<<(N + 255) / 256, 256, 0, stream>>>(rowptr, bsum, cursor, N);
  k_scatter<<<(E2 + 255) / 256, 256, 0, stream>>>(ei, E, N, cursor, srt);

  // layer-1 GEMM (bf16 MFMA) with fused attention-dot columns, fp8 h output
  k_gemm1m<<<(N + 63) / 64, 256, 0, stream>>>(x, Wg, h1f, as1, ad1, N);

  // fused layer-1 softmax+aggregate+ELU+GEMM2+att dots (blockwise)
  k_agg1f<<<(N + 3) / 4, 256, 0, stream>>>(rowptr, deg, srt, as1, ad1, h1f,
                                           b1, W2, ats2, atd2, nd2, N);

  // fused layer-2
  k_agg2f<<<(N + 15) / 16, 256, 0, stream>>>(rowptr, deg, srt, nd2, b2, out, N);
}

// Round 12
// 183.196 us; speedup vs baseline: 1.0379x; 1.0158x over previous
//
#include <hip/hip_runtime.h>
#include <hip/hip_bf16.h>
#include <math.h>

#define NEG_SLOPE 0.2f

typedef short bf16x8 __attribute__((ext_vector_type(8)));
typedef float f32x4 __attribute__((ext_vector_type(4)));
typedef _Float16 f16x8 __attribute__((ext_vector_type(8)));

__device__ __forceinline__ float lrelu(float x) { return fmaxf(x, NEG_SLOPE * x); }

__device__ __forceinline__ ushort f2bf(float f) {
  __hip_bfloat16 b = __float2bfloat16(f);
  return *reinterpret_cast<ushort*>(&b);
}

// ---------------- prep: Wg[144 cols][128 k] bf16, XOR-swizzled; also zeroes deg[].
// cols 0..127 = W1^T ; cols 128..135 = u_src[k][head] ; 136..143 = u_dst[k][head]
// where u[k][h] = sum_ch W1[k][h*16+ch] * att[h][ch]  (so  x @ u = h . att)
__global__ __launch_bounds__(256) void k_prep(
    const float* __restrict__ W1, const float* __restrict__ ats1, const float* __restrict__ atd1,
    ushort* __restrict__ Wg, int* __restrict__ deg, int N)
{
  int t = blockIdx.x * 256 + threadIdx.x;
  if (t < N) deg[t] = 0;
  if (t < 128 * 128) {
    int k = t >> 7, n = t & 127;
    Wg[(size_t)n * 128 + (k ^ ((n & 7) << 3))] = f2bf(W1[t]);
  } else if (t < 128 * 128 + 128 * 16) {
    int tt = t - 128 * 128;
    int k = tt >> 4;          // 0..127
    int c = tt & 15;          // 0..7 -> as, 8..15 -> ad
    int head = c & 7;
    const float* av = (c < 8) ? ats1 : atd1;
    float s = 0.f;
#pragma unroll
    for (int ch = 0; ch < 16; ++ch)
      s += W1[k * 128 + head * 16 + ch] * av[head * 16 + ch];
    int n = 128 + c;
    Wg[(size_t)n * 128 + (k ^ ((n & 7) << 3))] = f2bf(s);
  }
}

// ---------------- h1 = x @ W1 via bf16 MFMA, 64 nodes/block, 4 waves.
// 9 column tiles: 0..7 -> h1h (fp16), tile 8 -> as1/ad1 (fp32)
__global__ __launch_bounds__(256) void k_gemm1m(
    const float* __restrict__ x, const ushort* __restrict__ Wg,
    ushort* __restrict__ h1h, float* __restrict__ as1, float* __restrict__ ad1, int N)
{
  __shared__ ushort Wls[144 * 128];
  const int tid = threadIdx.x;
  const float4* Wg4 = (const float4*)Wg;
  float4* Wl4 = (float4*)Wls;
#pragma unroll
  for (int i = 0; i < 9; ++i) Wl4[tid + i * 256] = Wg4[tid + i * 256];
  __syncthreads();

  const int lane = tid & 63, wid = tid >> 6;
  const int r0 = blockIdx.x * 64 + wid * 16;
  const int lr = lane & 15, kg = lane >> 4;
  int row = r0 + lr; if (row >= N) row = N - 1;
  const float* xr = x + (size_t)row * 128;

  f32x4 acc[9];
#pragma unroll
  for (int i = 0; i < 9; ++i) acc[i] = (f32x4){0.f, 0.f, 0.f, 0.f};

#pragma unroll
  for (int ks = 0; ks < 4; ++ks) {
    int k0 = ks * 32 + kg * 8;
    float4 xa = *(const float4*)(xr + k0);
    float4 xb = *(const float4*)(xr + k0 + 4);
    bf16x8 af;
    af[0] = f2bf(xa.x); af[1] = f2bf(xa.y); af[2] = f2bf(xa.z); af[3] = f2bf(xa.w);
    af[4] = f2bf(xb.x); af[5] = f2bf(xb.y); af[6] = f2bf(xb.z); af[7] = f2bf(xb.w);
#pragma unroll
    for (int nt = 0; nt < 9; ++nt) {
      int n = nt * 16 + lr;
      bf16x8 bfr = *(const bf16x8*)(Wls + n * 128 + (k0 ^ ((n & 7) << 3)));
      acc[nt] = __builtin_amdgcn_mfma_f32_16x16x32_bf16(af, bfr, acc[nt], 0, 0, 0);
    }
  }
  // C layout: col = lane&15, row = (lane>>4)*4 + reg
#pragma unroll
  for (int nt = 0; nt < 8; ++nt) {
#pragma unroll
    for (int i = 0; i < 4; ++i) {
      int r = r0 + kg * 4 + i;
      if (r < N) {
        _Float16 hf = (_Float16)acc[nt][i];
        h1h[(size_t)r * 128 + nt * 16 + lr] = *reinterpret_cast<ushort*>(&hf);
      }
    }
  }
#pragma unroll
  for (int i = 0; i < 4; ++i) {
    int r = r0 + kg * 4 + i;
    if (r < N) {
      if (lr < 8) as1[(size_t)r * 8 + lr]     = acc[8][i];
      else        ad1[(size_t)r * 8 + lr - 8] = acc[8][i];
    }
  }
}

// ---------------- CSR build: histogram, 2-level exclusive scan, scatter
__global__ __launch_bounds__(256) void k_hist(const int* __restrict__ ei, int E, int N,
                                              int* __restrict__ deg) {
  int e = blockIdx.x * 256 + threadIdx.x;
  if (e >= E + N) return;
  int d = (e < E) ? ei[E + e] : e - E;
  atomicAdd(&deg[d], 1);
}

__global__ __launch_bounds__(256) void k_scan1(const int* __restrict__ deg,
                                               int* __restrict__ rowptr,
                                               int* __restrict__ bsum, int N) {
  __shared__ int sc[256];
  int b = blockIdx.x, t = threadIdx.x;
  int i0 = b * 512 + 2 * t, i1 = i0 + 1;
  int a = (i0 < N) ? deg[i0] : 0;
  int bb = (i1 < N) ? deg[i1] : 0;
  int s = a + bb;
  sc[t] = s; __syncthreads();
  int run = s;
  for (int dd = 1; dd < 256; dd <<= 1) {
    int v = (t >= dd) ? sc[t - dd] : 0; __syncthreads();
    run += v; sc[t] = run; __syncthreads();
  }
  int excl = run - s;
  if (i0 < N) rowptr[i0] = excl;
  if (i1 < N) rowptr[i1] = excl + a;
  if (t == 255) bsum[b] = run;
}

__global__ __launch_bounds__(256) void k_scan2(int* __restrict__ bsum, int nb) {
  __shared__ int sc[256];
  int t = threadIdx.x;
  int s = (t < nb) ? bsum[t] : 0;
  sc[t] = s; __syncthreads();
  int run = s;
  for (int dd = 1; dd < 256; dd <<= 1) {
    int v = (t >= dd) ? sc[t - dd] : 0; __syncthreads();
    run += v; sc[t] = run; __syncthreads();
  }
  if (t < nb) bsum[t] = run - s;
}

__global__ __launch_bounds__(256) void k_scan3(int* __restrict__ rowptr,
                                               const int* __restrict__ bsum,
                                               int* __restrict__ cursor, int N) {
  int i = blockIdx.x * 256 + threadIdx.x;
  if (i >= N) return;
  int v = rowptr[i] + bsum[i >> 9];
  rowptr[i] = v;
  cursor[i] = v;
}

__global__ __launch_bounds__(256) void k_scatter(const int* __restrict__ ei, int E, int N,
                                                 int* __restrict__ cursor,
                                                 int* __restrict__ srt) {
  int e = blockIdx.x * 256 + threadIdx.x;
  if (e >= E + N) return;
  int s, d;
  if (e < E) { s = ei[e]; d = ei[E + e]; } else { s = d = e - E; }
  int pos = atomicAdd(&cursor[d], 1);
  srt[pos] = s;
}

// ---------------- Fused layer-1, BLOCKWISE (4 dst/block); fp16 h rows + packed
// v_pk_fma_f16 accumulate; edge loop unrolled 4x (16 edges/wave/iter).
__global__ __launch_bounds__(256) void k_agg1f(
    const int* __restrict__ rowptr, const int* __restrict__ deg, const int* __restrict__ srt,
    const float* __restrict__ as1, const float* __restrict__ ad1,
    const _Float16* __restrict__ h1h,
    const float* __restrict__ b1, const float* __restrict__ W2,
    const float* __restrict__ ats2, const float* __restrict__ atd2,
    float4* __restrict__ nd2, int N)
{
  const int lane = threadIdx.x & 63;
  const int d = blockIdx.x * 4 + (threadIdx.x >> 6);
  if (d >= N) return;
  const int g = lane >> 4, l16 = lane & 15;
  const int hh = l16 >> 1;                 // head of this lane's 8 channels
  const int hoff = 8 * l16;

  const int start = rowptr[d];
  const int dg = deg[d];
  const float adh = ad1[d * 8 + hh];

  f16x8 acc = (f16x8)(_Float16)0.f;
  float sum = 0.f;

  int c = g;                                // this group's first edge
  int s0 = srt[start + min(c,      dg - 1)];
  int s1 = srt[start + min(c + 4,  dg - 1)];
  int s2 = srt[start + min(c + 8,  dg - 1)];
  int s3 = srt[start + min(c + 12, dg - 1)];
  while (c < dg) {
    int cn = c + 16;
    int t0 = srt[start + min(cn,      dg - 1)];
    int t1 = srt[start + min(cn + 4,  dg - 1)];
    int t2 = srt[start + min(cn + 8,  dg - 1)];
    int t3 = srt[start + min(cn + 12, dg - 1)];
    // issue all 4 batches' loads before consumption
    float av0 = as1[s0 * 8 + hh];
    f16x8 hv0 = *(const f16x8*)(h1h + s0 * 128 + hoff);
    float av1 = as1[s1 * 8 + hh];
    f16x8 hv1 = *(const f16x8*)(h1h + s1 * 128 + hoff);
    float av2 = as1[s2 * 8 + hh];
    f16x8 hv2 = *(const f16x8*)(h1h + s2 * 128 + hoff);
    float av3 = as1[s3 * 8 + hh];
    f16x8 hv3 = *(const f16x8*)(h1h + s3 * 128 + hoff);

    float au0 = __expf(lrelu(av0 + adh));                        // c < dg guaranteed
    float au1 = (c + 4  < dg) ? __expf(lrelu(av1 + adh)) : 0.f;
    float au2 = (c + 8  < dg) ? __expf(lrelu(av2 + adh)) : 0.f;
    float au3 = (c + 12 < dg) ? __expf(lrelu(av3 + adh)) : 0.f;
    sum += (au0 + au1) + (au2 + au3);
    _Float16 a0 = (_Float16)au0, a1 = (_Float16)au1;
    _Float16 a2 = (_Float16)au2, a3 = (_Float16)au3;
    acc += hv0 * a0;   // 4x v_pk_fma_f16 each
    acc += hv1 * a1;
    acc += hv2 * a2;
    acc += hv3 * a3;

    c = cn; s0 = t0; s1 = t1; s2 = t2; s3 = t3;
  }

  // cross-group reduction (lanes 16,32) in fp32
  float v[8];
#pragma unroll
  for (int j = 0; j < 8; ++j) {
    float t = (float)acc[j];
    t += __shfl_xor(t, 16);
    t += __shfl_xor(t, 32);
    v[j] = t;
  }
  sum += __shfl_xor(sum, 16); sum += __shfl_xor(sum, 32);
  const float inv = 1.f / (sum + 1e-16f);

  // epilogue: normalize, +b1, ELU (exp-1), GEMM2 (128->2), layer-2 att dots
  float4 b0 = *(const float4*)(b1 + hoff);
  float4 b4 = *(const float4*)(b1 + hoff + 4);
  v[0] = fmaf(v[0], inv, b0.x); v[1] = fmaf(v[1], inv, b0.y);
  v[2] = fmaf(v[2], inv, b0.z); v[3] = fmaf(v[3], inv, b0.w);
  v[4] = fmaf(v[4], inv, b4.x); v[5] = fmaf(v[5], inv, b4.y);
  v[6] = fmaf(v[6], inv, b4.z); v[7] = fmaf(v[7], inv, b4.w);
#pragma unroll
  for (int j = 0; j < 8; ++j) v[j] = v[j] > 0.f ? v[j] : (__expf(v[j]) - 1.f);

  const float4* W24 = (const float4*)(W2 + 16 * l16);
  float4 w0 = W24[0], w1 = W24[1], w2 = W24[2], w3 = W24[3];
  float p0 = v[0]*w0.x + v[1]*w0.z + v[2]*w1.x + v[3]*w1.z
           + v[4]*w2.x + v[5]*w2.z + v[6]*w3.x + v[7]*w3.z;
  float p1 = v[0]*w0.y + v[1]*w0.w + v[2]*w1.y + v[3]*w1.w
           + v[4]*w2.y + v[5]*w2.w + v[6]*w3.y + v[7]*w3.w;
#pragma unroll
  for (int m = 1; m < 16; m <<= 1) { p0 += __shfl_xor(p0, m); p1 += __shfl_xor(p1, m); }
  if (lane == 0) {
    float a2 = p0 * ats2[0] + p1 * ats2[1];
    float dd2 = p0 * atd2[0] + p1 * atd2[1];
    nd2[d] = make_float4(p0, p1, a2, dd2);
  }
}

// ---------------- Fused layer-2: 16 lanes per dst; one float4 load per edge
__global__ __launch_bounds__(256) void k_agg2f(
    const int* __restrict__ rowptr, const int* __restrict__ deg, const int* __restrict__ srt,
    const float4* __restrict__ nd2, const float* __restrict__ b2,
    float* __restrict__ out, int N)
{
  const int l16 = threadIdx.x & 15;
  const int d = blockIdx.x * 16 + (threadIdx.x >> 4);
  if (d >= N) return;
  const int start = rowptr[d];
  const int dg = deg[d];
  const float adv = nd2[d].w;

  float se = 0.f, a0 = 0.f, a1 = 0.f;
  for (int c = l16; c < dg; c += 16) {
    int s = srt[start + c];
    float4 r = nd2[s];
    float ex = __expf(lrelu(r.z + adv));
    se += ex;
    a0 = fmaf(ex, r.x, a0);
    a1 = fmaf(ex, r.y, a1);
  }
#pragma unroll
  for (int m = 1; m < 16; m <<= 1) {
    se += __shfl_xor(se, m, 16);
    a0 += __shfl_xor(a0, m, 16);
    a1 += __shfl_xor(a1, m, 16);
  }
  if (l16 == 0) {
    float invs = 1.f / (se + 1e-16f);
    out[(size_t)d * 2]     = a0 * invs + b2[0];
    out[(size_t)d * 2 + 1] = a1 * invs + b2[1];
  }
}

extern "C" void kernel_launch(void* const* d_in, const int* in_sizes, int n_in,
                              void* d_out, int out_size, void* d_ws, size_t ws_size,
                              hipStream_t stream) {
  const float* x    = (const float*)d_in[0];
  const int*   ei   = (const int*)d_in[1];
  const float* W1   = (const float*)d_in[2];
  const float* ats1 = (const float*)d_in[3];
  const float* atd1 = (const float*)d_in[4];
  const float* b1   = (const float*)d_in[5];
  const float* W2   = (const float*)d_in[6];
  const float* ats2 = (const float*)d_in[7];
  const float* atd2 = (const float*)d_in[8];
  const float* b2   = (const float*)d_in[9];
  float* out = (float*)d_out;

  const int N  = in_sizes[0] / 128;
  const int E  = in_sizes[1] / 2;
  const int E2 = E + N;
  const int nb = (N + 511) / 512;

  // workspace layout (floats)
  float* ws = (float*)d_ws;
  size_t off = 0;
  _Float16* h1h = (_Float16*)(ws + off); off += (size_t)N * 64;  // N*128 fp16
  float* as1 = ws + off; off += (size_t)N * 8;
  float* ad1 = ws + off; off += (size_t)N * 8;
  float4* nd2 = (float4*)(ws + off); off += (size_t)N * 4;
  int* deg    = (int*)(ws + off); off += (size_t)N;
  int* rowptr = (int*)(ws + off); off += (size_t)N;
  int* cursor = (int*)(ws + off); off += (size_t)N;
  int* bsum   = (int*)(ws + off); off += 256;
  int* srt    = (int*)(ws + off); off += (size_t)E2;
  ushort* Wg  = (ushort*)(ws + off); off += 144 * 64;         // 144*128 bf16

  // prep (also zeroes deg) must run before hist
  const int prep_blocks = max((128 * 128 + 128 * 16 + 255) / 256, (N + 255) / 256);
  k_prep<<<prep_blocks, 256, 0, stream>>>(W1, ats1, atd1, Wg, deg, N);

  // CSR build (shared by both layers)
  k_hist<<<(E2 + 255) / 256, 256, 0, stream>>>(ei, E, N, deg);
  k_scan1<<<nb, 256, 0, stream>>>(deg, rowptr, bsum, N);
  k_scan2<<<1, 256, 0, stream>>>(bsum, nb);
  k_scan3<<<(N + 255) / 256, 256, 0, stream>>>(rowptr, bsum, cursor, N);
  k_scatter<<<(E2 + 255) / 256, 256, 0, stream>>>(ei, E, N, cursor, srt);

  // layer-1 GEMM (bf16 MFMA) with fused attention-dot columns, fp16 h output
  k_gemm1m<<<(N + 63) / 64, 256, 0, stream>>>(x, Wg, (ushort*)h1h, as1, ad1, N);

  // fused layer-1 softmax+aggregate+ELU+GEMM2+att dots (blockwise, unroll-4)
  k_agg1f<<<(N + 3) / 4, 256, 0, stream>>>(rowptr, deg, srt, as1, ad1, h1h,
                                           b1, W2, ats2, atd2, nd2, N);

  // fused layer-2
  k_agg2f<<<(N + 15) / 16, 256, 0, stream>>>(rowptr, deg, srt, nd2, b2, out, N);
}

// Round 13
// 181.699 us; speedup vs baseline: 1.0464x; 1.0082x over previous
//
#include <hip/hip_runtime.h>
#include <hip/hip_bf16.h>
#include <math.h>

#define NEG_SLOPE 0.2f

typedef short bf16x8 __attribute__((ext_vector_type(8)));
typedef float f32x4 __attribute__((ext_vector_type(4)));
typedef float f32x2 __attribute__((ext_vector_type(2)));
typedef _Float16 f16x2 __attribute__((ext_vector_type(2)));

__device__ __forceinline__ float lrelu(float x) { return fmaxf(x, NEG_SLOPE * x); }

__device__ __forceinline__ ushort f2bf(float f) {
  __hip_bfloat16 b = __float2bfloat16(f);
  return *reinterpret_cast<ushort*>(&b);
}

// fp8 e4m3 (OCP on gfx950) scalar encode: low byte of packed result
__device__ __forceinline__ unsigned char f2fp8(float f) {
  return (unsigned char)(__builtin_amdgcn_cvt_pk_fp8_f32(f, f, 0, false) & 0xFF);
}

// decode 2 packed fp8 -> 2 fp16 (single HW op on gfx950; guarded fallback)
__device__ __forceinline__ f16x2 fp8x2_f16x2(unsigned w) {
#if defined(__has_builtin) && __has_builtin(__builtin_amdgcn_cvt_pk_f16_fp8)
  return __builtin_amdgcn_cvt_pk_f16_fp8((short)w);
#else
  f32x2 p = __builtin_amdgcn_cvt_pk_f32_fp8(w, 0);
  return (f16x2){(_Float16)p[0], (_Float16)p[1]};
#endif
}

// ---------------- prep: Wg[144 cols][128 k] bf16, XOR-swizzled; also zeroes deg[].
// cols 0..127 = W1^T ; cols 128..135 = u_src[k][head] ; 136..143 = u_dst[k][head]
// where u[k][h] = sum_ch W1[k][h*16+ch] * att[h][ch]  (so  x @ u = h . att)
__global__ __launch_bounds__(256) void k_prep(
    const float* __restrict__ W1, const float* __restrict__ ats1, const float* __restrict__ atd1,
    ushort* __restrict__ Wg, int* __restrict__ deg, int N)
{
  int t = blockIdx.x * 256 + threadIdx.x;
  if (t < N) deg[t] = 0;
  if (t < 128 * 128) {
    int k = t >> 7, n = t & 127;
    Wg[(size_t)n * 128 + (k ^ ((n & 7) << 3))] = f2bf(W1[t]);
  } else if (t < 128 * 128 + 128 * 16) {
    int tt = t - 128 * 128;
    int k = tt >> 4;          // 0..127
    int c = tt & 15;          // 0..7 -> as, 8..15 -> ad
    int head = c & 7;
    const float* av = (c < 8) ? ats1 : atd1;
    float s = 0.f;
#pragma unroll
    for (int ch = 0; ch < 16; ++ch)
      s += W1[k * 128 + head * 16 + ch] * av[head * 16 + ch];
    int n = 128 + c;
    Wg[(size_t)n * 128 + (k ^ ((n & 7) << 3))] = f2bf(s);
  }
}

// ---------------- h1 = x @ W1 via bf16 MFMA, 64 nodes/block, 4 waves.
// 9 column tiles: 0..7 -> h1f (fp8 e4m3), tile 8 -> as1/ad1 (fp32)
__global__ __launch_bounds__(256) void k_gemm1m(
    const float* __restrict__ x, const ushort* __restrict__ Wg,
    unsigned char* __restrict__ h1f, float* __restrict__ as1, float* __restrict__ ad1, int N)
{
  __shared__ ushort Wls[144 * 128];
  const int tid = threadIdx.x;
  const float4* Wg4 = (const float4*)Wg;
  float4* Wl4 = (float4*)Wls;
#pragma unroll
  for (int i = 0; i < 9; ++i) Wl4[tid + i * 256] = Wg4[tid + i * 256];
  __syncthreads();

  const int lane = tid & 63, wid = tid >> 6;
  const int r0 = blockIdx.x * 64 + wid * 16;
  const int lr = lane & 15, kg = lane >> 4;
  int row = r0 + lr; if (row >= N) row = N - 1;
  const float* xr = x + (size_t)row * 128;

  f32x4 acc[9];
#pragma unroll
  for (int i = 0; i < 9; ++i) acc[i] = (f32x4){0.f, 0.f, 0.f, 0.f};

#pragma unroll
  for (int ks = 0; ks < 4; ++ks) {
    int k0 = ks * 32 + kg * 8;
    float4 xa = *(const float4*)(xr + k0);
    float4 xb = *(const float4*)(xr + k0 + 4);
    bf16x8 af;
    af[0] = f2bf(xa.x); af[1] = f2bf(xa.y); af[2] = f2bf(xa.z); af[3] = f2bf(xa.w);
    af[4] = f2bf(xb.x); af[5] = f2bf(xb.y); af[6] = f2bf(xb.z); af[7] = f2bf(xb.w);
#pragma unroll
    for (int nt = 0; nt < 9; ++nt) {
      int n = nt * 16 + lr;
      bf16x8 bfr = *(const bf16x8*)(Wls + n * 128 + (k0 ^ ((n & 7) << 3)));
      acc[nt] = __builtin_amdgcn_mfma_f32_16x16x32_bf16(af, bfr, acc[nt], 0, 0, 0);
    }
  }
  // C layout: col = lane&15, row = (lane>>4)*4 + reg
#pragma unroll
  for (int nt = 0; nt < 8; ++nt) {
#pragma unroll
    for (int i = 0; i < 4; ++i) {
      int r = r0 + kg * 4 + i;
      if (r < N) h1f[(size_t)r * 128 + nt * 16 + lr] = f2fp8(acc[nt][i]);
    }
  }
#pragma unroll
  for (int i = 0; i < 4; ++i) {
    int r = r0 + kg * 4 + i;
    if (r < N) {
      if (lr < 8) as1[(size_t)r * 8 + lr]     = acc[8][i];
      else        ad1[(size_t)r * 8 + lr - 8] = acc[8][i];
    }
  }
}

// ---------------- CSR build: histogram, 2-level exclusive scan, scatter
__global__ __launch_bounds__(256) void k_hist(const int* __restrict__ ei, int E, int N,
                                              int* __restrict__ deg) {
  int e = blockIdx.x * 256 + threadIdx.x;
  if (e >= E + N) return;
  int d = (e < E) ? ei[E + e] : e - E;
  atomicAdd(&deg[d], 1);
}

__global__ __launch_bounds__(256) void k_scan1(const int* __restrict__ deg,
                                               int* __restrict__ rowptr,
                                               int* __restrict__ bsum, int N) {
  __shared__ int sc[256];
  int b = blockIdx.x, t = threadIdx.x;
  int i0 = b * 512 + 2 * t, i1 = i0 + 1;
  int a = (i0 < N) ? deg[i0] : 0;
  int bb = (i1 < N) ? deg[i1] : 0;
  int s = a + bb;
  sc[t] = s; __syncthreads();
  int run = s;
  for (int dd = 1; dd < 256; dd <<= 1) {
    int v = (t >= dd) ? sc[t - dd] : 0; __syncthreads();
    run += v; sc[t] = run; __syncthreads();
  }
  int excl = run - s;
  if (i0 < N) rowptr[i0] = excl;
  if (i1 < N) rowptr[i1] = excl + a;
  if (t == 255) bsum[b] = run;
}

__global__ __launch_bounds__(256) void k_scan2(int* __restrict__ bsum, int nb) {
  __shared__ int sc[256];
  int t = threadIdx.x;
  int s = (t < nb) ? bsum[t] : 0;
  sc[t] = s; __syncthreads();
  int run = s;
  for (int dd = 1; dd < 256; dd <<= 1) {
    int v = (t >= dd) ? sc[t - dd] : 0; __syncthreads();
    run += v; sc[t] = run; __syncthreads();
  }
  if (t < nb) bsum[t] = run - s;
}

__global__ __launch_bounds__(256) void k_scan3(int* __restrict__ rowptr,
                                               const int* __restrict__ bsum,
                                               int* __restrict__ cursor, int N) {
  int i = blockIdx.x * 256 + threadIdx.x;
  if (i >= N) return;
  int v = rowptr[i] + bsum[i >> 9];
  rowptr[i] = v;
  cursor[i] = v;
}

__global__ __launch_bounds__(256) void k_scatter(const int* __restrict__ ei, int E, int N,
                                                 int* __restrict__ cursor,
                                                 int* __restrict__ srt) {
  int e = blockIdx.x * 256 + threadIdx.x;
  if (e >= E + N) return;
  int s, d;
  if (e < E) { s = ei[e]; d = ei[E + e]; } else { s = d = e - E; }
  int pos = atomicAdd(&cursor[d], 1);
  srt[pos] = s;
}

// ---------------- Fused layer-1, BLOCKWISE (4 dst/block); fp8 h rows (128 B = ONE
// cache line per edge) decoded via v_cvt_pk_f16_fp8 into packed v_pk_fma_f16;
// edge loop unrolled 4x (16 edges/wave/iter).
__global__ __launch_bounds__(256) void k_agg1f(
    const int* __restrict__ rowptr, const int* __restrict__ deg, const int* __restrict__ srt,
    const float* __restrict__ as1, const float* __restrict__ ad1,
    const unsigned char* __restrict__ h1f,
    const float* __restrict__ b1, const float* __restrict__ W2,
    const float* __restrict__ ats2, const float* __restrict__ atd2,
    float4* __restrict__ nd2, int N)
{
  const int lane = threadIdx.x & 63;
  const int d = blockIdx.x * 4 + (threadIdx.x >> 6);
  if (d >= N) return;
  const int g = lane >> 4, l16 = lane & 15;
  const int hh = l16 >> 1;                 // head of this lane's 8 channels
  const int hoff = 8 * l16;                // byte offset into fp8 row == channel idx

  const int start = rowptr[d];
  const int dg = deg[d];
  const float adh = ad1[d * 8 + hh];

  f16x2 ac0 = {0, 0}, ac1 = {0, 0}, ac2 = {0, 0}, ac3 = {0, 0};
  float sum = 0.f;

#define EDGEACC(hv, au) { \
    _Float16 ah = (_Float16)(au); f16x2 av2 = {ah, ah}; \
    ac0 += fp8x2_f16x2((hv).x & 0xffffu) * av2; \
    ac1 += fp8x2_f16x2((hv).x >> 16)     * av2; \
    ac2 += fp8x2_f16x2((hv).y & 0xffffu) * av2; \
    ac3 += fp8x2_f16x2((hv).y >> 16)     * av2; \
  }

  int c = g;                                // this group's first edge
  int s0 = srt[start + min(c,      dg - 1)];
  int s1 = srt[start + min(c + 4,  dg - 1)];
  int s2 = srt[start + min(c + 8,  dg - 1)];
  int s3 = srt[start + min(c + 12, dg - 1)];
  while (c < dg) {
    int cn = c + 16;
    int t0 = srt[start + min(cn,      dg - 1)];
    int t1 = srt[start + min(cn + 4,  dg - 1)];
    int t2 = srt[start + min(cn + 8,  dg - 1)];
    int t3 = srt[start + min(cn + 12, dg - 1)];
    // issue all 4 batches' loads before consumption
    float av0 = as1[s0 * 8 + hh];
    uint2 hv0 = *(const uint2*)(h1f + s0 * 128 + hoff);
    float av1 = as1[s1 * 8 + hh];
    uint2 hv1 = *(const uint2*)(h1f + s1 * 128 + hoff);
    float av2v = as1[s2 * 8 + hh];
    uint2 hv2 = *(const uint2*)(h1f + s2 * 128 + hoff);
    float av3 = as1[s3 * 8 + hh];
    uint2 hv3 = *(const uint2*)(h1f + s3 * 128 + hoff);

    float au0 = __expf(lrelu(av0 + adh));                        // c < dg guaranteed
    float au1 = (c + 4  < dg) ? __expf(lrelu(av1 + adh))  : 0.f;
    float au2 = (c + 8  < dg) ? __expf(lrelu(av2v + adh)) : 0.f;
    float au3 = (c + 12 < dg) ? __expf(lrelu(av3 + adh))  : 0.f;
    sum += (au0 + au1) + (au2 + au3);
    EDGEACC(hv0, au0);
    EDGEACC(hv1, au1);
    EDGEACC(hv2, au2);
    EDGEACC(hv3, au3);

    c = cn; s0 = t0; s1 = t1; s2 = t2; s3 = t3;
  }
#undef EDGEACC

  // cross-group reduction (lanes 16,32) in fp32
  float v[8] = {(float)ac0[0], (float)ac0[1], (float)ac1[0], (float)ac1[1],
                (float)ac2[0], (float)ac2[1], (float)ac3[0], (float)ac3[1]};
#pragma unroll
  for (int j = 0; j < 8; ++j) {
    v[j] += __shfl_xor(v[j], 16);
    v[j] += __shfl_xor(v[j], 32);
  }
  sum += __shfl_xor(sum, 16); sum += __shfl_xor(sum, 32);
  const float inv = 1.f / (sum + 1e-16f);

  // epilogue: normalize, +b1, ELU (exp-1), GEMM2 (128->2), layer-2 att dots
  float4 b0 = *(const float4*)(b1 + hoff);
  float4 b4 = *(const float4*)(b1 + hoff + 4);
  v[0] = fmaf(v[0], inv, b0.x); v[1] = fmaf(v[1], inv, b0.y);
  v[2] = fmaf(v[2], inv, b0.z); v[3] = fmaf(v[3], inv, b0.w);
  v[4] = fmaf(v[4], inv, b4.x); v[5] = fmaf(v[5], inv, b4.y);
  v[6] = fmaf(v[6], inv, b4.z); v[7] = fmaf(v[7], inv, b4.w);
#pragma unroll
  for (int j = 0; j < 8; ++j) v[j] = v[j] > 0.f ? v[j] : (__expf(v[j]) - 1.f);

  const float4* W24 = (const float4*)(W2 + 16 * l16);
  float4 w0 = W24[0], w1 = W24[1], w2 = W24[2], w3 = W24[3];
  float p0 = v[0]*w0.x + v[1]*w0.z + v[2]*w1.x + v[3]*w1.z
           + v[4]*w2.x + v[5]*w2.z + v[6]*w3.x + v[7]*w3.z;
  float p1 = v[0]*w0.y + v[1]*w0.w + v[2]*w1.y + v[3]*w1.w
           + v[4]*w2.y + v[5]*w2.w + v[6]*w3.y + v[7]*w3.w;
#pragma unroll
  for (int m = 1; m < 16; m <<= 1) { p0 += __shfl_xor(p0, m); p1 += __shfl_xor(p1, m); }
  if (lane == 0) {
    float a2 = p0 * ats2[0] + p1 * ats2[1];
    float dd2 = p0 * atd2[0] + p1 * atd2[1];
    nd2[d] = make_float4(p0, p1, a2, dd2);
  }
}

// ---------------- Fused layer-2: 16 lanes per dst; one float4 load per edge
__global__ __launch_bounds__(256) void k_agg2f(
    const int* __restrict__ rowptr, const int* __restrict__ deg, const int* __restrict__ srt,
    const float4* __restrict__ nd2, const float* __restrict__ b2,
    float* __restrict__ out, int N)
{
  const int l16 = threadIdx.x & 15;
  const int d = blockIdx.x * 16 + (threadIdx.x >> 4);
  if (d >= N) return;
  const int start = rowptr[d];
  const int dg = deg[d];
  const float adv = nd2[d].w;

  float se = 0.f, a0 = 0.f, a1 = 0.f;
  for (int c = l16; c < dg; c += 16) {
    int s = srt[start + c];
    float4 r = nd2[s];
    float ex = __expf(lrelu(r.z + adv));
    se += ex;
    a0 = fmaf(ex, r.x, a0);
    a1 = fmaf(ex, r.y, a1);
  }
#pragma unroll
  for (int m = 1; m < 16; m <<= 1) {
    se += __shfl_xor(se, m, 16);
    a0 += __shfl_xor(a0, m, 16);
    a1 += __shfl_xor(a1, m, 16);
  }
  if (l16 == 0) {
    float invs = 1.f / (se + 1e-16f);
    out[(size_t)d * 2]     = a0 * invs + b2[0];
    out[(size_t)d * 2 + 1] = a1 * invs + b2[1];
  }
}

extern "C" void kernel_launch(void* const* d_in, const int* in_sizes, int n_in,
                              void* d_out, int out_size, void* d_ws, size_t ws_size,
                              hipStream_t stream) {
  const float* x    = (const float*)d_in[0];
  const int*   ei   = (const int*)d_in[1];
  const float* W1   = (const float*)d_in[2];
  const float* ats1 = (const float*)d_in[3];
  const float* atd1 = (const float*)d_in[4];
  const float* b1   = (const float*)d_in[5];
  const float* W2   = (const float*)d_in[6];
  const float* ats2 = (const float*)d_in[7];
  const float* atd2 = (const float*)d_in[8];
  const float* b2   = (const float*)d_in[9];
  float* out = (float*)d_out;

  const int N  = in_sizes[0] / 128;
  const int E  = in_sizes[1] / 2;
  const int E2 = E + N;
  const int nb = (N + 511) / 512;

  // workspace layout (floats)
  float* ws = (float*)d_ws;
  size_t off = 0;
  unsigned char* h1f = (unsigned char*)(ws + off); off += (size_t)N * 32;  // N*128 fp8
  float* as1 = ws + off; off += (size_t)N * 8;
  float* ad1 = ws + off; off += (size_t)N * 8;
  float4* nd2 = (float4*)(ws + off); off += (size_t)N * 4;
  int* deg    = (int*)(ws + off); off += (size_t)N;
  int* rowptr = (int*)(ws + off); off += (size_t)N;
  int* cursor = (int*)(ws + off); off += (size_t)N;
  int* bsum   = (int*)(ws + off); off += 256;
  int* srt    = (int*)(ws + off); off += (size_t)E2;
  ushort* Wg  = (ushort*)(ws + off); off += 144 * 64;         // 144*128 bf16

  // prep (also zeroes deg) must run before hist
  const int prep_blocks = max((128 * 128 + 128 * 16 + 255) / 256, (N + 255) / 256);
  k_prep<<<prep_blocks, 256, 0, stream>>>(W1, ats1, atd1, Wg, deg, N);

  // CSR build (shared by both layers)
  k_hist<<<(E2 + 255) / 256, 256, 0, stream>>>(ei, E, N, deg);
  k_scan1<<<nb, 256, 0, stream>>>(deg, rowptr, bsum, N);
  k_scan2<<<1, 256, 0, stream>>>(bsum, nb);
  k_scan3<<<(N + 255) / 256, 256, 0, stream>>>(rowptr, bsum, cursor, N);
  k_scatter<<<(E2 + 255) / 256, 256, 0, stream>>>(ei, E, N, cursor, srt);

  // layer-1 GEMM (bf16 MFMA) with fused attention-dot columns, fp8 h output
  k_gemm1m<<<(N + 63) / 64, 256, 0, stream>>>(x, Wg, h1f, as1, ad1, N);

  // fused layer-1 softmax+aggregate+ELU+GEMM2+att dots (blockwise, unroll-4)
  k_agg1f<<<(N + 3) / 4, 256, 0, stream>>>(rowptr, deg, srt, as1, ad1, h1f,
                                           b1, W2, ats2, atd2, nd2, N);

  // fused layer-2
  k_agg2f<<<(N + 15) / 16, 256, 0, stream>>>(rowptr, deg, srt, nd2, b2, out, N);
}

// Round 14
// 178.569 us; speedup vs baseline: 1.0648x; 1.0175x over previous
//
#include <hip/hip_runtime.h>
#include <hip/hip_bf16.h>
#include <math.h>

#define NEG_SLOPE 0.2f

typedef short bf16x8 __attribute__((ext_vector_type(8)));
typedef float f32x4 __attribute__((ext_vector_type(4)));
typedef float f32x2 __attribute__((ext_vector_type(2)));
typedef _Float16 f16x2 __attribute__((ext_vector_type(2)));

__device__ __forceinline__ float lrelu(float x) { return fmaxf(x, NEG_SLOPE * x); }

__device__ __forceinline__ ushort f2bf(float f) {
  __hip_bfloat16 b = __float2bfloat16(f);
  return *reinterpret_cast<ushort*>(&b);
}

// fp8 e4m3 (OCP on gfx950) scalar encode: low byte of packed result
__device__ __forceinline__ unsigned char f2fp8(float f) {
  return (unsigned char)(__builtin_amdgcn_cvt_pk_fp8_f32(f, f, 0, false) & 0xFF);
}

// decode 2 packed fp8 -> 2 fp16 (single HW op on gfx950; guarded fallback)
__device__ __forceinline__ f16x2 fp8x2_f16x2(unsigned w) {
#if defined(__has_builtin) && __has_builtin(__builtin_amdgcn_cvt_pk_f16_fp8)
  return __builtin_amdgcn_cvt_pk_f16_fp8((short)w);
#else
  f32x2 p = __builtin_amdgcn_cvt_pk_f32_fp8(w, 0);
  return (f16x2){(_Float16)p[0], (_Float16)p[1]};
#endif
}

// ---------------- prep: Wg[144 cols][128 k] bf16, XOR-swizzled; also zeroes deg[].
__global__ __launch_bounds__(256) void k_prep(
    const float* __restrict__ W1, const float* __restrict__ ats1, const float* __restrict__ atd1,
    ushort* __restrict__ Wg, int* __restrict__ deg, int N)
{
  int t = blockIdx.x * 256 + threadIdx.x;
  if (t < N) deg[t] = 0;
  if (t < 128 * 128) {
    int k = t >> 7, n = t & 127;
    Wg[(size_t)n * 128 + (k ^ ((n & 7) << 3))] = f2bf(W1[t]);
  } else if (t < 128 * 128 + 128 * 16) {
    int tt = t - 128 * 128;
    int k = tt >> 4;          // 0..127
    int c = tt & 15;          // 0..7 -> as, 8..15 -> ad
    int head = c & 7;
    const float* av = (c < 8) ? ats1 : atd1;
    float s = 0.f;
#pragma unroll
    for (int ch = 0; ch < 16; ++ch)
      s += W1[k * 128 + head * 16 + ch] * av[head * 16 + ch];
    int n = 128 + c;
    Wg[(size_t)n * 128 + (k ^ ((n & 7) << 3))] = f2bf(s);
  }
}

// ---------------- h1 = x @ W1 via bf16 MFMA, 64 nodes/block, 4 waves.
// 9 column tiles: 0..7 -> h1f (fp8 e4m3), tile 8 -> as1/ad1 (fp32)
__global__ __launch_bounds__(256) void k_gemm1m(
    const float* __restrict__ x, const ushort* __restrict__ Wg,
    unsigned char* __restrict__ h1f, float* __restrict__ as1, float* __restrict__ ad1, int N)
{
  __shared__ ushort Wls[144 * 128];
  const int tid = threadIdx.x;
  const float4* Wg4 = (const float4*)Wg;
  float4* Wl4 = (float4*)Wls;
#pragma unroll
  for (int i = 0; i < 9; ++i) Wl4[tid + i * 256] = Wg4[tid + i * 256];
  __syncthreads();

  const int lane = tid & 63, wid = tid >> 6;
  const int r0 = blockIdx.x * 64 + wid * 16;
  const int lr = lane & 15, kg = lane >> 4;
  int row = r0 + lr; if (row >= N) row = N - 1;
  const float* xr = x + (size_t)row * 128;

  f32x4 acc[9];
#pragma unroll
  for (int i = 0; i < 9; ++i) acc[i] = (f32x4){0.f, 0.f, 0.f, 0.f};

#pragma unroll
  for (int ks = 0; ks < 4; ++ks) {
    int k0 = ks * 32 + kg * 8;
    float4 xa = *(const float4*)(xr + k0);
    float4 xb = *(const float4*)(xr + k0 + 4);
    bf16x8 af;
    af[0] = f2bf(xa.x); af[1] = f2bf(xa.y); af[2] = f2bf(xa.z); af[3] = f2bf(xa.w);
    af[4] = f2bf(xb.x); af[5] = f2bf(xb.y); af[6] = f2bf(xb.z); af[7] = f2bf(xb.w);
#pragma unroll
    for (int nt = 0; nt < 9; ++nt) {
      int n = nt * 16 + lr;
      bf16x8 bfr = *(const bf16x8*)(Wls + n * 128 + (k0 ^ ((n & 7) << 3)));
      acc[nt] = __builtin_amdgcn_mfma_f32_16x16x32_bf16(af, bfr, acc[nt], 0, 0, 0);
    }
  }
  // C layout: col = lane&15, row = (lane>>4)*4 + reg
#pragma unroll
  for (int nt = 0; nt < 8; ++nt) {
#pragma unroll
    for (int i = 0; i < 4; ++i) {
      int r = r0 + kg * 4 + i;
      if (r < N) h1f[(size_t)r * 128 + nt * 16 + lr] = f2fp8(acc[nt][i]);
    }
  }
#pragma unroll
  for (int i = 0; i < 4; ++i) {
    int r = r0 + kg * 4 + i;
    if (r < N) {
      if (lr < 8) as1[(size_t)r * 8 + lr]     = acc[8][i];
      else        ad1[(size_t)r * 8 + lr - 8] = acc[8][i];
    }
  }
}

// ---------------- CSR build: histogram, 2-level exclusive scan
__global__ __launch_bounds__(256) void k_hist(const int* __restrict__ ei, int E, int N,
                                              int* __restrict__ deg) {
  int e = blockIdx.x * 256 + threadIdx.x;
  if (e >= E + N) return;
  int d = (e < E) ? ei[E + e] : e - E;
  atomicAdd(&deg[d], 1);
}

__global__ __launch_bounds__(256) void k_scan1(const int* __restrict__ deg,
                                               int* __restrict__ rowptr,
                                               int* __restrict__ bsum, int N) {
  __shared__ int sc[256];
  int b = blockIdx.x, t = threadIdx.x;
  int i0 = b * 512 + 2 * t, i1 = i0 + 1;
  int a = (i0 < N) ? deg[i0] : 0;
  int bb = (i1 < N) ? deg[i1] : 0;
  int s = a + bb;
  sc[t] = s; __syncthreads();
  int run = s;
  for (int dd = 1; dd < 256; dd <<= 1) {
    int v = (t >= dd) ? sc[t - dd] : 0; __syncthreads();
    run += v; sc[t] = run; __syncthreads();
  }
  int excl = run - s;
  if (i0 < N) rowptr[i0] = excl;
  if (i1 < N) rowptr[i1] = excl + a;
  if (t == 255) bsum[b] = run;
}

__global__ __launch_bounds__(256) void k_scan2(int* __restrict__ bsum, int nb) {
  __shared__ int sc[256];
  int t = threadIdx.x;
  int s = (t < nb) ? bsum[t] : 0;
  sc[t] = s; __syncthreads();
  int run = s;
  for (int dd = 1; dd < 256; dd <<= 1) {
    int v = (t >= dd) ? sc[t - dd] : 0; __syncthreads();
    run += v; sc[t] = run; __syncthreads();
  }
  if (t < nb) bsum[t] = run - s;
}

__global__ __launch_bounds__(256) void k_scan3(int* __restrict__ rowptr,
                                               const int* __restrict__ bsum,
                                               int* __restrict__ cursor, int N) {
  int i = blockIdx.x * 256 + threadIdx.x;
  if (i >= N) return;
  int v = rowptr[i] + bsum[i >> 9];
  rowptr[i] = v;
  cursor[i] = v;
}

// ---------------- scatter2: sorted scatter + per-edge per-head attention numerator
// 8 lanes per edge (lane = head). One v_exp instruction covers 8 edges x 8 heads.
// au8[pos][h] = exp(lrelu(as1[s][h] + ad1[d][h])), f16, at the SORTED position.
__global__ __launch_bounds__(256) void k_scatter2(
    const int* __restrict__ ei, int E, int N,
    const float* __restrict__ as1, const float* __restrict__ ad1,
    int* __restrict__ cursor, int* __restrict__ srt, _Float16* __restrict__ au8)
{
  const int lane = threadIdx.x & 63;
  const int h = lane & 7, eg = lane >> 3;
  const int e = (blockIdx.x * 4 + (threadIdx.x >> 6)) * 8 + eg;   // 32 edges/block
  if (e >= E + N) return;
  int s, d;
  if (e < E) { s = ei[e]; d = ei[E + e]; } else { s = d = e - E; }
  float a = as1[s * 8 + h] + ad1[d * 8 + h];
  float au = __expf(lrelu(a));
  int pos = 0;
  if (h == 0) pos = atomicAdd(&cursor[d], 1);
  pos = __shfl(pos, eg << 3);
  au8[pos * 8 + h] = (_Float16)au;
  if (h == 0) srt[pos] = s;
}

// ---------------- Fused layer-1, BLOCKWISE (4 dst/block); fp8 h rows (1 line/edge),
// attention weights pre-computed (au8, sequential per node). No exp in the loop.
__global__ __launch_bounds__(256) void k_agg1f(
    const int* __restrict__ rowptr, const int* __restrict__ deg, const int* __restrict__ srt,
    const _Float16* __restrict__ au8, const unsigned char* __restrict__ h1f,
    const float* __restrict__ b1, const float* __restrict__ W2,
    const float* __restrict__ ats2, const float* __restrict__ atd2,
    float4* __restrict__ nd2, int N)
{
  const int lane = threadIdx.x & 63;
  const int d = blockIdx.x * 4 + (threadIdx.x >> 6);
  if (d >= N) return;
  const int g = lane >> 4, l16 = lane & 15;
  const int hh = l16 >> 1;                 // head of this lane's 8 channels
  const int hoff = 8 * l16;                // byte offset into fp8 row

  const int start = rowptr[d];
  const int dg = deg[d];

  f16x2 ac0 = {0, 0}, ac1 = {0, 0}, ac2 = {0, 0}, ac3 = {0, 0};
  float sum = 0.f;

#define EDGEACC(hv, ah) { \
    f16x2 av2 = {(ah), (ah)}; \
    ac0 += fp8x2_f16x2((hv).x & 0xffffu) * av2; \
    ac1 += fp8x2_f16x2((hv).x >> 16)     * av2; \
    ac2 += fp8x2_f16x2((hv).y & 0xffffu) * av2; \
    ac3 += fp8x2_f16x2((hv).y >> 16)     * av2; \
  }

  int c = g;                                // this group's first edge
  int s0 = srt[start + min(c,      dg - 1)];
  int s1 = srt[start + min(c + 4,  dg - 1)];
  int s2 = srt[start + min(c + 8,  dg - 1)];
  int s3 = srt[start + min(c + 12, dg - 1)];
  while (c < dg) {
    int cn = c + 16;
    int t0 = srt[start + min(cn,      dg - 1)];
    int t1 = srt[start + min(cn + 4,  dg - 1)];
    int t2 = srt[start + min(cn + 8,  dg - 1)];
    int t3 = srt[start + min(cn + 12, dg - 1)];
    // issue all loads before consumption (au8 is sequential per node)
    _Float16 u0 = au8[(start + c) * 8 + hh];                     // c < dg guaranteed
    uint2 hv0 = *(const uint2*)(h1f + s0 * 128 + hoff);
    _Float16 u1 = au8[(start + min(c + 4,  dg - 1)) * 8 + hh];
    uint2 hv1 = *(const uint2*)(h1f + s1 * 128 + hoff);
    _Float16 u2 = au8[(start + min(c + 8,  dg - 1)) * 8 + hh];
    uint2 hv2 = *(const uint2*)(h1f + s2 * 128 + hoff);
    _Float16 u3 = au8[(start + min(c + 12, dg - 1)) * 8 + hh];
    uint2 hv3 = *(const uint2*)(h1f + s3 * 128 + hoff);

    const _Float16 zz = (_Float16)0.f;
    u1 = (c + 4  < dg) ? u1 : zz;
    u2 = (c + 8  < dg) ? u2 : zz;
    u3 = (c + 12 < dg) ? u3 : zz;
    sum += (float)u0 + (float)u1 + (float)u2 + (float)u3;
    EDGEACC(hv0, u0);
    EDGEACC(hv1, u1);
    EDGEACC(hv2, u2);
    EDGEACC(hv3, u3);

    c = cn; s0 = t0; s1 = t1; s2 = t2; s3 = t3;
  }
#undef EDGEACC

  // cross-group reduction (lanes 16,32) in fp32
  float v[8] = {(float)ac0[0], (float)ac0[1], (float)ac1[0], (float)ac1[1],
                (float)ac2[0], (float)ac2[1], (float)ac3[0], (float)ac3[1]};
#pragma unroll
  for (int j = 0; j < 8; ++j) {
    v[j] += __shfl_xor(v[j], 16);
    v[j] += __shfl_xor(v[j], 32);
  }
  sum += __shfl_xor(sum, 16); sum += __shfl_xor(sum, 32);
  const float inv = 1.f / (sum + 1e-16f);

  // epilogue: normalize, +b1, ELU (exp-1), GEMM2 (128->2), layer-2 att dots
  float4 b0 = *(const float4*)(b1 + hoff);
  float4 b4 = *(const float4*)(b1 + hoff + 4);
  v[0] = fmaf(v[0], inv, b0.x); v[1] = fmaf(v[1], inv, b0.y);
  v[2] = fmaf(v[2], inv, b0.z); v[3] = fmaf(v[3], inv, b0.w);
  v[4] = fmaf(v[4], inv, b4.x); v[5] = fmaf(v[5], inv, b4.y);
  v[6] = fmaf(v[6], inv, b4.z); v[7] = fmaf(v[7], inv, b4.w);
#pragma unroll
  for (int j = 0; j < 8; ++j) v[j] = v[j] > 0.f ? v[j] : (__expf(v[j]) - 1.f);

  const float4* W24 = (const float4*)(W2 + 16 * l16);
  float4 w0 = W24[0], w1 = W24[1], w2 = W24[2], w3 = W24[3];
  float p0 = v[0]*w0.x + v[1]*w0.z + v[2]*w1.x + v[3]*w1.z
           + v[4]*w2.x + v[5]*w2.z + v[6]*w3.x + v[7]*w3.z;
  float p1 = v[0]*w0.y + v[1]*w0.w + v[2]*w1.y + v[3]*w1.w
           + v[4]*w2.y + v[5]*w2.w + v[6]*w3.y + v[7]*w3.w;
#pragma unroll
  for (int m = 1; m < 16; m <<= 1) { p0 += __shfl_xor(p0, m); p1 += __shfl_xor(p1, m); }
  if (lane == 0) {
    float a2 = p0 * ats2[0] + p1 * ats2[1];
    float dd2 = p0 * atd2[0] + p1 * atd2[1];
    nd2[d] = make_float4(p0, p1, a2, dd2);
  }
}

// ---------------- Fused layer-2: 16 lanes per dst; one float4 load per edge
__global__ __launch_bounds__(256) void k_agg2f(
    const int* __restrict__ rowptr, const int* __restrict__ deg, const int* __restrict__ srt,
    const float4* __restrict__ nd2, const float* __restrict__ b2,
    float* __restrict__ out, int N)
{
  const int l16 = threadIdx.x & 15;
  const int d = blockIdx.x * 16 + (threadIdx.x >> 4);
  if (d >= N) return;
  const int start = rowptr[d];
  const int dg = deg[d];
  const float adv = nd2[d].w;

  float se = 0.f, a0 = 0.f, a1 = 0.f;
  for (int c = l16; c < dg; c += 16) {
    int s = srt[start + c];
    float4 r = nd2[s];
    float ex = __expf(lrelu(r.z + adv));
    se += ex;
    a0 = fmaf(ex, r.x, a0);
    a1 = fmaf(ex, r.y, a1);
  }
#pragma unroll
  for (int m = 1; m < 16; m <<= 1) {
    se += __shfl_xor(se, m, 16);
    a0 += __shfl_xor(a0, m, 16);
    a1 += __shfl_xor(a1, m, 16);
  }
  if (l16 == 0) {
    float invs = 1.f / (se + 1e-16f);
    out[(size_t)d * 2]     = a0 * invs + b2[0];
    out[(size_t)d * 2 + 1] = a1 * invs + b2[1];
  }
}

extern "C" void kernel_launch(void* const* d_in, const int* in_sizes, int n_in,
                              void* d_out, int out_size, void* d_ws, size_t ws_size,
                              hipStream_t stream) {
  const float* x    = (const float*)d_in[0];
  const int*   ei   = (const int*)d_in[1];
  const float* W1   = (const float*)d_in[2];
  const float* ats1 = (const float*)d_in[3];
  const float* atd1 = (const float*)d_in[4];
  const float* b1   = (const float*)d_in[5];
  const float* W2   = (const float*)d_in[6];
  const float* ats2 = (const float*)d_in[7];
  const float* atd2 = (const float*)d_in[8];
  const float* b2   = (const float*)d_in[9];
  float* out = (float*)d_out;

  const int N  = in_sizes[0] / 128;
  const int E  = in_sizes[1] / 2;
  const int E2 = E + N;
  const int nb = (N + 511) / 512;

  // workspace layout (floats)
  float* ws = (float*)d_ws;
  size_t off = 0;
  unsigned char* h1f = (unsigned char*)(ws + off); off += (size_t)N * 32;  // N*128 fp8
  float* as1 = ws + off; off += (size_t)N * 8;
  float* ad1 = ws + off; off += (size_t)N * 8;
  float4* nd2 = (float4*)(ws + off); off += (size_t)N * 4;
  int* deg    = (int*)(ws + off); off += (size_t)N;
  int* rowptr = (int*)(ws + off); off += (size_t)N;
  int* cursor = (int*)(ws + off); off += (size_t)N;
  int* bsum   = (int*)(ws + off); off += 256;
  int* srt    = (int*)(ws + off); off += (size_t)E2;
  _Float16* au8 = (_Float16*)(ws + off); off += (size_t)E2 * 4;  // E2*8 f16
  ushort* Wg  = (ushort*)(ws + off); off += 144 * 64;            // 144*128 bf16

  // prep (also zeroes deg) must run before hist
  const int prep_blocks = max((128 * 128 + 128 * 16 + 255) / 256, (N + 255) / 256);
  k_prep<<<prep_blocks, 256, 0, stream>>>(W1, ats1, atd1, Wg, deg, N);

  // layer-1 GEMM (needed by scatter2 for as1/ad1)
  k_gemm1m<<<(N + 63) / 64, 256, 0, stream>>>(x, Wg, h1f, as1, ad1, N);

  // CSR build
  k_hist<<<(E2 + 255) / 256, 256, 0, stream>>>(ei, E, N, deg);
  k_scan1<<<nb, 256, 0, stream>>>(deg, rowptr, bsum, N);
  k_scan2<<<1, 256, 0, stream>>>(bsum, nb);
  k_scan3<<<(N + 255) / 256, 256, 0, stream>>>(rowptr, bsum, cursor, N);
  k_scatter2<<<(E2 + 31) / 32, 256, 0, stream>>>(ei, E, N, as1, ad1, cursor, srt, au8);

  // fused layer-1 softmax+aggregate+ELU+GEMM2+att dots (blockwise, unroll-4)
  k_agg1f<<<(N + 3) / 4, 256, 0, stream>>>(rowptr, deg, srt, au8, h1f,
                                           b1, W2, ats2, atd2, nd2, N);

  // fused layer-2
  k_agg2f<<<(N + 15) / 16, 256, 0, stream>>>(rowptr, deg, srt, nd2, b2, out, N);
}

// Round 15
// 155.445 us; speedup vs baseline: 1.2232x; 1.1488x over previous
//
#include <hip/hip_runtime.h>
#include <hip/hip_bf16.h>
#include <math.h>

#define NEG_SLOPE 0.2f

typedef short bf16x8 __attribute__((ext_vector_type(8)));
typedef float f32x4 __attribute__((ext_vector_type(4)));
typedef float f32x2 __attribute__((ext_vector_type(2)));
typedef _Float16 f16x2 __attribute__((ext_vector_type(2)));

__device__ __forceinline__ float lrelu(float x) { return fmaxf(x, NEG_SLOPE * x); }

__device__ __forceinline__ ushort f2bf(float f) {
  __hip_bfloat16 b = __float2bfloat16(f);
  return *reinterpret_cast<ushort*>(&b);
}

// fp8 e4m3 (OCP on gfx950) scalar encode: low byte of packed result
__device__ __forceinline__ unsigned char f2fp8(float f) {
  return (unsigned char)(__builtin_amdgcn_cvt_pk_fp8_f32(f, f, 0, false) & 0xFF);
}

// decode 2 packed fp8 -> 2 fp16 (single HW op on gfx950; guarded fallback)
__device__ __forceinline__ f16x2 fp8x2_f16x2(unsigned w) {
#if defined(__has_builtin) && __has_builtin(__builtin_amdgcn_cvt_pk_f16_fp8)
  return __builtin_amdgcn_cvt_pk_f16_fp8((short)w);
#else
  f32x2 p = __builtin_amdgcn_cvt_pk_f32_fp8(w, 0);
  return (f16x2){(_Float16)p[0], (_Float16)p[1]};
#endif
}

// ---------------- prep: Wg[144 cols][128 k] bf16, XOR-swizzled; also zeroes deg[].
__global__ __launch_bounds__(256) void k_prep(
    const float* __restrict__ W1, const float* __restrict__ ats1, const float* __restrict__ atd1,
    ushort* __restrict__ Wg, int* __restrict__ deg, int N)
{
  int t = blockIdx.x * 256 + threadIdx.x;
  if (t < N) deg[t] = 0;
  if (t < 128 * 128) {
    int k = t >> 7, n = t & 127;
    Wg[(size_t)n * 128 + (k ^ ((n & 7) << 3))] = f2bf(W1[t]);
  } else if (t < 128 * 128 + 128 * 16) {
    int tt = t - 128 * 128;
    int k = tt >> 4;          // 0..127
    int c = tt & 15;          // 0..7 -> as, 8..15 -> ad
    int head = c & 7;
    const float* av = (c < 8) ? ats1 : atd1;
    float s = 0.f;
#pragma unroll
    for (int ch = 0; ch < 16; ++ch)
      s += W1[k * 128 + head * 16 + ch] * av[head * 16 + ch];
    int n = 128 + c;
    Wg[(size_t)n * 128 + (k ^ ((n & 7) << 3))] = f2bf(s);
  }
}

// ---------------- h1 = x @ W1 via bf16 MFMA, 64 nodes/block, 4 waves.
// 9 column tiles: 0..7 -> h1f (fp8 e4m3), tile 8 -> as1/ad1 (fp32)
__global__ __launch_bounds__(256) void k_gemm1m(
    const float* __restrict__ x, const ushort* __restrict__ Wg,
    unsigned char* __restrict__ h1f, float* __restrict__ as1, float* __restrict__ ad1, int N)
{
  __shared__ ushort Wls[144 * 128];
  const int tid = threadIdx.x;
  const float4* Wg4 = (const float4*)Wg;
  float4* Wl4 = (float4*)Wls;
#pragma unroll
  for (int i = 0; i < 9; ++i) Wl4[tid + i * 256] = Wg4[tid + i * 256];
  __syncthreads();

  const int lane = tid & 63, wid = tid >> 6;
  const int r0 = blockIdx.x * 64 + wid * 16;
  const int lr = lane & 15, kg = lane >> 4;
  int row = r0 + lr; if (row >= N) row = N - 1;
  const float* xr = x + (size_t)row * 128;

  f32x4 acc[9];
#pragma unroll
  for (int i = 0; i < 9; ++i) acc[i] = (f32x4){0.f, 0.f, 0.f, 0.f};

#pragma unroll
  for (int ks = 0; ks < 4; ++ks) {
    int k0 = ks * 32 + kg * 8;
    float4 xa = *(const float4*)(xr + k0);
    float4 xb = *(const float4*)(xr + k0 + 4);
    bf16x8 af;
    af[0] = f2bf(xa.x); af[1] = f2bf(xa.y); af[2] = f2bf(xa.z); af[3] = f2bf(xa.w);
    af[4] = f2bf(xb.x); af[5] = f2bf(xb.y); af[6] = f2bf(xb.z); af[7] = f2bf(xb.w);
#pragma unroll
    for (int nt = 0; nt < 9; ++nt) {
      int n = nt * 16 + lr;
      bf16x8 bfr = *(const bf16x8*)(Wls + n * 128 + (k0 ^ ((n & 7) << 3)));
      acc[nt] = __builtin_amdgcn_mfma_f32_16x16x32_bf16(af, bfr, acc[nt], 0, 0, 0);
    }
  }
  // C layout: col = lane&15, row = (lane>>4)*4 + reg
#pragma unroll
  for (int nt = 0; nt < 8; ++nt) {
#pragma unroll
    for (int i = 0; i < 4; ++i) {
      int r = r0 + kg * 4 + i;
      if (r < N) h1f[(size_t)r * 128 + nt * 16 + lr] = f2fp8(acc[nt][i]);
    }
  }
#pragma unroll
  for (int i = 0; i < 4; ++i) {
    int r = r0 + kg * 4 + i;
    if (r < N) {
      if (lr < 8) as1[(size_t)r * 8 + lr]     = acc[8][i];
      else        ad1[(size_t)r * 8 + lr - 8] = acc[8][i];
    }
  }
}

// ---------------- CSR build: histogram, 2-level exclusive scan
__global__ __launch_bounds__(256) void k_hist(const int* __restrict__ ei, int E, int N,
                                              int* __restrict__ deg) {
  int e = blockIdx.x * 256 + threadIdx.x;
  if (e >= E + N) return;
  int d = (e < E) ? ei[E + e] : e - E;
  atomicAdd(&deg[d], 1);
}

__global__ __launch_bounds__(256) void k_scan1(const int* __restrict__ deg,
                                               int* __restrict__ rowptr,
                                               int* __restrict__ bsum, int N) {
  __shared__ int sc[256];
  int b = blockIdx.x, t = threadIdx.x;
  int i0 = b * 512 + 2 * t, i1 = i0 + 1;
  int a = (i0 < N) ? deg[i0] : 0;
  int bb = (i1 < N) ? deg[i1] : 0;
  int s = a + bb;
  sc[t] = s; __syncthreads();
  int run = s;
  for (int dd = 1; dd < 256; dd <<= 1) {
    int v = (t >= dd) ? sc[t - dd] : 0; __syncthreads();
    run += v; sc[t] = run; __syncthreads();
  }
  int excl = run - s;
  if (i0 < N) rowptr[i0] = excl;
  if (i1 < N) rowptr[i1] = excl + a;
  if (t == 255) bsum[b] = run;
}

__global__ __launch_bounds__(256) void k_scan2(int* __restrict__ bsum, int nb) {
  __shared__ int sc[256];
  int t = threadIdx.x;
  int s = (t < nb) ? bsum[t] : 0;
  sc[t] = s; __syncthreads();
  int run = s;
  for (int dd = 1; dd < 256; dd <<= 1) {
    int v = (t >= dd) ? sc[t - dd] : 0; __syncthreads();
    run += v; sc[t] = run; __syncthreads();
  }
  if (t < nb) bsum[t] = run - s;
}

__global__ __launch_bounds__(256) void k_scan3(int* __restrict__ rowptr,
                                               const int* __restrict__ bsum,
                                               int* __restrict__ cursor, int N) {
  int i = blockIdx.x * 256 + threadIdx.x;
  if (i >= N) return;
  int v = rowptr[i] + bsum[i >> 9];
  rowptr[i] = v;
  cursor[i] = v;
}

// ---------------- scatter2: sorted scatter + per-edge per-head attention numerator
// 8 lanes per edge (lane = head). au8[pos][h] = exp(lrelu(as1[s][h]+ad1[d][h])), f16.
__global__ __launch_bounds__(256) void k_scatter2(
    const int* __restrict__ ei, int E, int N,
    const float* __restrict__ as1, const float* __restrict__ ad1,
    int* __restrict__ cursor, int* __restrict__ srt, _Float16* __restrict__ au8)
{
  const int lane = threadIdx.x & 63;
  const int h = lane & 7, eg = lane >> 3;
  const int e = (blockIdx.x * 4 + (threadIdx.x >> 6)) * 8 + eg;   // 32 edges/block
  if (e >= E + N) return;
  int s, d;
  if (e < E) { s = ei[e]; d = ei[E + e]; } else { s = d = e - E; }
  float a = as1[s * 8 + h] + ad1[d * 8 + h];
  float au = __expf(lrelu(a));
  int pos = 0;
  if (h == 0) pos = atomicAdd(&cursor[d], 1);
  pos = __shfl(pos, eg << 3);
  au8[pos * 8 + h] = (_Float16)au;
  if (h == 0) srt[pos] = s;
}

// ---------------- Fused layer-1: FOUR dst nodes per wave (16 lanes each).
// No cross-group reduction; epilogue amortized 4x. fp8 h rows, au8 precomputed.
__global__ __launch_bounds__(256) void k_agg1f(
    const int* __restrict__ rowptr, const int* __restrict__ deg, const int* __restrict__ srt,
    const _Float16* __restrict__ au8, const unsigned char* __restrict__ h1f,
    const float* __restrict__ b1, const float* __restrict__ W2,
    const float* __restrict__ ats2, const float* __restrict__ atd2,
    float4* __restrict__ nd2, int N)
{
  const int lane = threadIdx.x & 63;
  const int wid = threadIdx.x >> 6;
  const int grp = lane >> 4, l16 = lane & 15;
  const int d0 = blockIdx.x * 16 + wid * 4 + grp;
  const int d = min(d0, N - 1);
  const int hh = l16 >> 1;                 // head of this lane's 8 channels
  const int hoff = 8 * l16;                // byte offset into fp8 row

  const int start = rowptr[d];
  const int dg = deg[d];
  const int dgm1 = dg - 1;                 // >= 0 (self-loops)
  const int* sp = srt + start;
  const _Float16* up = au8 + start * 8 + hh;

  f16x2 ac0 = {0, 0}, ac1 = {0, 0}, ac2 = {0, 0}, ac3 = {0, 0};
  float sum = 0.f;

#define EDGEACC(hv, ah) { \
    f16x2 av2 = {(ah), (ah)}; \
    ac0 += fp8x2_f16x2((hv).x & 0xffffu) * av2; \
    ac1 += fp8x2_f16x2((hv).x >> 16)     * av2; \
    ac2 += fp8x2_f16x2((hv).y & 0xffffu) * av2; \
    ac3 += fp8x2_f16x2((hv).y >> 16)     * av2; \
  }

  int c = 0;
  int s0 = sp[0];
  int s1 = sp[min(1, dgm1)];
  int s2 = sp[min(2, dgm1)];
  int s3 = sp[min(3, dgm1)];
  while (c < dg) {
    int cn = c + 4;
    int t0 = sp[min(cn,     dgm1)];
    int t1 = sp[min(cn + 1, dgm1)];
    int t2 = sp[min(cn + 2, dgm1)];
    int t3 = sp[min(cn + 3, dgm1)];
    // issue all loads before consumption (au8 sequential per node)
    _Float16 u0 = up[min(c,     dgm1) * 8];
    uint2 hv0 = *(const uint2*)(h1f + s0 * 128 + hoff);
    _Float16 u1 = up[min(c + 1, dgm1) * 8];
    uint2 hv1 = *(const uint2*)(h1f + s1 * 128 + hoff);
    _Float16 u2 = up[min(c + 2, dgm1) * 8];
    uint2 hv2 = *(const uint2*)(h1f + s2 * 128 + hoff);
    _Float16 u3 = up[min(c + 3, dgm1) * 8];
    uint2 hv3 = *(const uint2*)(h1f + s3 * 128 + hoff);

    const _Float16 zz = (_Float16)0.f;
    u1 = (c + 1 < dg) ? u1 : zz;
    u2 = (c + 2 < dg) ? u2 : zz;
    u3 = (c + 3 < dg) ? u3 : zz;
    sum += (float)u0 + (float)u1 + (float)u2 + (float)u3;
    EDGEACC(hv0, u0);
    EDGEACC(hv1, u1);
    EDGEACC(hv2, u2);
    EDGEACC(hv3, u3);

    c = cn; s0 = t0; s1 = t1; s2 = t2; s3 = t3;
  }
#undef EDGEACC

  // no cross-group reduction: each 16-lane group holds its node's full 128 channels,
  // and each lane's head-sum is complete (all lanes saw all edges).
  float v[8] = {(float)ac0[0], (float)ac0[1], (float)ac1[0], (float)ac1[1],
                (float)ac2[0], (float)ac2[1], (float)ac3[0], (float)ac3[1]};
  const float inv = 1.f / (sum + 1e-16f);

  // epilogue: normalize, +b1, ELU (exp-1), GEMM2 (128->2), layer-2 att dots
  float4 b0 = *(const float4*)(b1 + hoff);
  float4 b4 = *(const float4*)(b1 + hoff + 4);
  v[0] = fmaf(v[0], inv, b0.x); v[1] = fmaf(v[1], inv, b0.y);
  v[2] = fmaf(v[2], inv, b0.z); v[3] = fmaf(v[3], inv, b0.w);
  v[4] = fmaf(v[4], inv, b4.x); v[5] = fmaf(v[5], inv, b4.y);
  v[6] = fmaf(v[6], inv, b4.z); v[7] = fmaf(v[7], inv, b4.w);
#pragma unroll
  for (int j = 0; j < 8; ++j) v[j] = v[j] > 0.f ? v[j] : (__expf(v[j]) - 1.f);

  const float4* W24 = (const float4*)(W2 + 16 * l16);
  float4 w0 = W24[0], w1 = W24[1], w2 = W24[2], w3 = W24[3];
  float p0 = v[0]*w0.x + v[1]*w0.z + v[2]*w1.x + v[3]*w1.z
           + v[4]*w2.x + v[5]*w2.z + v[6]*w3.x + v[7]*w3.z;
  float p1 = v[0]*w0.y + v[1]*w0.w + v[2]*w1.y + v[3]*w1.w
           + v[4]*w2.y + v[5]*w2.w + v[6]*w3.y + v[7]*w3.w;
#pragma unroll
  for (int m = 1; m < 16; m <<= 1) { p0 += __shfl_xor(p0, m); p1 += __shfl_xor(p1, m); }
  if (l16 == 0 && d0 < N) {
    float a2 = p0 * ats2[0] + p1 * ats2[1];
    float dd2 = p0 * atd2[0] + p1 * atd2[1];
    nd2[d0] = make_float4(p0, p1, a2, dd2);
  }
}

// ---------------- Fused layer-2: 16 lanes per dst; one float4 load per edge
__global__ __launch_bounds__(256) void k_agg2f(
    const int* __restrict__ rowptr, const int* __restrict__ deg, const int* __restrict__ srt,
    const float4* __restrict__ nd2, const float* __restrict__ b2,
    float* __restrict__ out, int N)
{
  const int l16 = threadIdx.x & 15;
  const int d = blockIdx.x * 16 + (threadIdx.x >> 4);
  if (d >= N) return;
  const int start = rowptr[d];
  const int dg = deg[d];
  const float adv = nd2[d].w;

  float se = 0.f, a0 = 0.f, a1 = 0.f;
  for (int c = l16; c < dg; c += 16) {
    int s = srt[start + c];
    float4 r = nd2[s];
    float ex = __expf(lrelu(r.z + adv));
    se += ex;
    a0 = fmaf(ex, r.x, a0);
    a1 = fmaf(ex, r.y, a1);
  }
#pragma unroll
  for (int m = 1; m < 16; m <<= 1) {
    se += __shfl_xor(se, m, 16);
    a0 += __shfl_xor(a0, m, 16);
    a1 += __shfl_xor(a1, m, 16);
  }
  if (l16 == 0) {
    float invs = 1.f / (se + 1e-16f);
    out[(size_t)d * 2]     = a0 * invs + b2[0];
    out[(size_t)d * 2 + 1] = a1 * invs + b2[1];
  }
}

extern "C" void kernel_launch(void* const* d_in, const int* in_sizes, int n_in,
                              void* d_out, int out_size, void* d_ws, size_t ws_size,
                              hipStream_t stream) {
  const float* x    = (const float*)d_in[0];
  const int*   ei   = (const int*)d_in[1];
  const float* W1   = (const float*)d_in[2];
  const float* ats1 = (const float*)d_in[3];
  const float* atd1 = (const float*)d_in[4];
  const float* b1   = (const float*)d_in[5];
  const float* W2   = (const float*)d_in[6];
  const float* ats2 = (const float*)d_in[7];
  const float* atd2 = (const float*)d_in[8];
  const float* b2   = (const float*)d_in[9];
  float* out = (float*)d_out;

  const int N  = in_sizes[0] / 128;
  const int E  = in_sizes[1] / 2;
  const int E2 = E + N;
  const int nb = (N + 511) / 512;

  // workspace layout (floats)
  float* ws = (float*)d_ws;
  size_t off = 0;
  unsigned char* h1f = (unsigned char*)(ws + off); off += (size_t)N * 32;  // N*128 fp8
  float* as1 = ws + off; off += (size_t)N * 8;
  float* ad1 = ws + off; off += (size_t)N * 8;
  float4* nd2 = (float4*)(ws + off); off += (size_t)N * 4;
  int* deg    = (int*)(ws + off); off += (size_t)N;
  int* rowptr = (int*)(ws + off); off += (size_t)N;
  int* cursor = (int*)(ws + off); off += (size_t)N;
  int* bsum   = (int*)(ws + off); off += 256;
  int* srt    = (int*)(ws + off); off += (size_t)E2;
  _Float16* au8 = (_Float16*)(ws + off); off += (size_t)E2 * 4;  // E2*8 f16
  ushort* Wg  = (ushort*)(ws + off); off += 144 * 64;            // 144*128 bf16

  // prep (also zeroes deg) must run before hist
  const int prep_blocks = max((128 * 128 + 128 * 16 + 255) / 256, (N + 255) / 256);
  k_prep<<<prep_blocks, 256, 0, stream>>>(W1, ats1, atd1, Wg, deg, N);

  // layer-1 GEMM (needed by scatter2 for as1/ad1)
  k_gemm1m<<<(N + 63) / 64, 256, 0, stream>>>(x, Wg, h1f, as1, ad1, N);

  // CSR build
  k_hist<<<(E2 + 255) / 256, 256, 0, stream>>>(ei, E, N, deg);
  k_scan1<<<nb, 256, 0, stream>>>(deg, rowptr, bsum, N);
  k_scan2<<<1, 256, 0, stream>>>(bsum, nb);
  k_scan3<<<(N + 255) / 256, 256, 0, stream>>>(rowptr, bsum, cursor, N);
  k_scatter2<<<(E2 + 31) / 32, 256, 0, stream>>>(ei, E, N, as1, ad1, cursor, srt, au8);

  // fused layer-1 softmax+aggregate+ELU+GEMM2+att dots (4 nodes/wave)
  k_agg1f<<<(N + 15) / 16, 256, 0, stream>>>(rowptr, deg, srt, au8, h1f,
                                             b1, W2, ats2, atd2, nd2, N);

  // fused layer-2
  k_agg2f<<<(N + 15) / 16, 256, 0, stream>>>(rowptr, deg, srt, nd2, b2, out, N);
}